// Round 1
// baseline (3321.373 us; speedup 1.0000x reference)
//
#include <hip/hip_runtime.h>

#define NN   8192
#define DEG  16
#define HID  128
#define IND  128
#define ED   8
#define NBLK 256

typedef __bf16 bf16_t;
typedef __bf16 bf16x8 __attribute__((ext_vector_type(8)));
typedef float  f32x4  __attribute__((ext_vector_type(4)));
typedef unsigned long long u64;

static __device__ __forceinline__ f32x4 mfma16(bf16x8 a, bf16x8 b, f32x4 c) {
  return __builtin_amdgcn_mfma_f32_16x16x32_bf16(a, b, c, 0, 0, 0);
}

// ---------------- kernel 1: h0 = x @ Wp + bp ; init flags ----------------
__global__ __launch_bounds__(128) void k_h0(const float* __restrict__ x,
                                            const float* __restrict__ Wp,
                                            const float* __restrict__ bp,
                                            float* __restrict__ h,
                                            int* __restrict__ flags) {
  __shared__ float sx[8][IND];
  const int t  = threadIdx.x;      // 0..127 = output channel
  const int vb = blockIdx.x * 8;   // 8 nodes per block
  #pragma unroll
  for (int rr = 0; rr < 8; ++rr) sx[rr][t] = x[(size_t)(vb + rr) * IND + t];
  __syncthreads();
  float acc[8];
  const float bias = bp[t];
  #pragma unroll
  for (int rr = 0; rr < 8; ++rr) acc[rr] = bias;
  for (int k = 0; k < IND; ++k) {
    const float w = Wp[k * HID + t];
    #pragma unroll
    for (int rr = 0; rr < 8; ++rr) acc[rr] += sx[rr][k] * w;
  }
  #pragma unroll
  for (int rr = 0; rr < 8; ++rr) h[(size_t)(vb + rr) * HID + t] = acc[rr];
  if (t < 8) flags[vb + t] = (vb + t == 0) ? 1 : 0;  // only node 0 starts "done"
}

// ---------------- kernel 2: persistent DAG executor ----------------
// 256 blocks (1 per CU, all co-resident), 4 waves/block, each wave owns two
// 16-channel output tiles of every layer. All weight fragments (bf16 hi/lo)
// are register-resident. Inter-node sync: agent-scope atomics via MALL.
#define LOAD_WFRAGS(W, KROWS, NKK, ARRH, ARRL)                                \
  _Pragma("unroll")                                                           \
  for (int n = 0; n < 2; ++n) {                                               \
    _Pragma("unroll")                                                         \
    for (int kk = 0; kk < NKK; ++kk) {                                        \
      _Pragma("unroll")                                                       \
      for (int i = 0; i < 8; ++i) {                                           \
        const int k = kk * 32 + g * 8 + i;                                    \
        const float w = (k < KROWS) ? W[k * HID + cc[n]] : 0.f;               \
        const bf16_t wh = (bf16_t)w;                                          \
        ARRH[n][kk][i] = wh;                                                  \
        ARRL[n][kk][i] = (bf16_t)(w - (float)wh);                             \
      }                                                                       \
    }                                                                         \
  }

__global__ __launch_bounds__(256, 1) void k_dag(
    const int* __restrict__ ei, const float* __restrict__ attr,
    const float* __restrict__ Wm1, const float* __restrict__ bm1,
    const float* __restrict__ Wm2, const float* __restrict__ bm2,
    const float* __restrict__ Wu1, const float* __restrict__ bu1,
    const float* __restrict__ Wu2, const float* __restrict__ bu2,
    float* __restrict__ h, int* __restrict__ flags) {
  const int tid  = threadIdx.x;
  const int lane = tid & 63;
  const int g    = lane >> 4;   // 16-lane group: k-block for A/B operands
  const int r    = lane & 15;   // A-row / B-col within tile
  const int wid  = tid >> 6;    // wave 0..3

  __shared__ int    s_src[DEG];
  __shared__ bf16_t s_m1[16 * HID];   // msg1 activations, chunk-XOR swizzled
  __shared__ float  s_agg[HID];
  __shared__ float  s_u1[HID];

  int cc[2];
  cc[0] = (wid * 2 + 0) * 16 + r;
  cc[1] = (wid * 2 + 1) * 16 + r;

  // ---- register-resident weight fragments (hi/lo bf16 split) ----
  bf16x8 wm1h[2][5], wm1l[2][5], wm2h[2][4], wm2l[2][4];
  bf16x8 wu1h[2][8], wu1l[2][8], wu2h[2][4], wu2l[2][4];
  LOAD_WFRAGS(Wm1, 136, 5, wm1h, wm1l)   // rows 0..127 = h part, 128..135 = attr part
  LOAD_WFRAGS(Wm2, 128, 4, wm2h, wm2l)
  LOAD_WFRAGS(Wu1, 256, 8, wu1h, wu1l)
  LOAD_WFRAGS(Wu2, 128, 4, wu2h, wu2l)
  float bs_m1[2], bs_m2[2], bs_u1[2], bs_u2[2];
  #pragma unroll
  for (int n = 0; n < 2; ++n) {
    bs_m1[n] = bm1[cc[n]]; bs_m2[n] = bm2[cc[n]];
    bs_u1[n] = bu1[cc[n]]; bs_u2[n] = bu2[cc[n]];
  }

  for (int v = 1 + (int)blockIdx.x; v < NN; v += NBLK) {
    // ---- wait for the 16 predecessors ----
    if (tid < DEG) {
      const int s = ei[(v - 1) * DEG + tid];
      s_src[tid] = s;
      int guard = 0;
      while (__hip_atomic_load(&flags[s], __ATOMIC_ACQUIRE,
                               __HIP_MEMORY_SCOPE_AGENT) == 0) {
        __builtin_amdgcn_s_sleep(1);
        if (++guard > (1 << 18)) break;  // fail-safe: wrong answer, never a hang
      }
    }
    __syncthreads();

    // ---- gather A fragments: pred rows (hi/lo, via MALL) + attr ----
    bf16x8 ah[5], al[5];
    {
      const int src = s_src[r];
      const u64* hp = (const u64*)(h + (size_t)src * HID) + g * 4;
      #pragma unroll
      for (int kk = 0; kk < 4; ++kk) {
        u64 q[4];
        #pragma unroll
        for (int u = 0; u < 4; ++u)
          q[u] = __hip_atomic_load(hp + kk * 16 + u, __ATOMIC_RELAXED,
                                   __HIP_MEMORY_SCOPE_AGENT);
        #pragma unroll
        for (int u = 0; u < 4; ++u) {
          #pragma unroll
          for (int b = 0; b < 2; ++b) {
            const float f = __uint_as_float((unsigned)(q[u] >> (32 * b)));
            const bf16_t fh = (bf16_t)f;
            ah[kk][u * 2 + b] = fh;
            al[kk][u * 2 + b] = (bf16_t)(f - (float)fh);
          }
        }
      }
      #pragma unroll
      for (int i = 0; i < 8; ++i) { ah[4][i] = (bf16_t)0.f; al[4][i] = (bf16_t)0.f; }
      if (g == 0) {  // attr occupies logical k = 128..135
        const f32x4* ap = (const f32x4*)(attr + ((size_t)(v - 1) * DEG + r) * ED);
        const f32x4 a0 = ap[0], a1 = ap[1];
        #pragma unroll
        for (int i = 0; i < 4; ++i) {
          ah[4][i] = (bf16_t)a0[i]; ah[4][4 + i] = (bf16_t)a1[i];
        }
      }
    }

    // ---- prefetch h0_v (first half of the update-MLP input) ----
    float hv[32];
    {
      const float* hvp = h + (size_t)v * HID + g * 8;
      #pragma unroll
      for (int kk = 0; kk < 4; ++kk) {
        const f32x4 p0 = *(const f32x4*)(hvp + kk * 32);
        const f32x4 p1 = *(const f32x4*)(hvp + kk * 32 + 4);
        #pragma unroll
        for (int i = 0; i < 4; ++i) { hv[kk*8 + i] = p0[i]; hv[kk*8 + 4 + i] = p1[i]; }
      }
    }

    // ---- msg layer 1 ----
    f32x4 m1[2];
    #pragma unroll
    for (int n = 0; n < 2; ++n) { m1[n][0]=bs_m1[n]; m1[n][1]=bs_m1[n]; m1[n][2]=bs_m1[n]; m1[n][3]=bs_m1[n]; }
    #pragma unroll
    for (int kk = 0; kk < 4; ++kk) {
      #pragma unroll
      for (int n = 0; n < 2; ++n) {
        m1[n] = mfma16(ah[kk], wm1h[n][kk], m1[n]);
        m1[n] = mfma16(ah[kk], wm1l[n][kk], m1[n]);
        m1[n] = mfma16(al[kk], wm1h[n][kk], m1[n]);
      }
    }
    #pragma unroll
    for (int n = 0; n < 2; ++n) {     // attr k-step (lo of attr negligible: averaged noise)
      m1[n] = mfma16(ah[4], wm1h[n][4], m1[n]);
      m1[n] = mfma16(ah[4], wm1l[n][4], m1[n]);
    }
    // relu -> bf16 -> LDS with chunk-XOR swizzle (conflict-free b128 reads)
    #pragma unroll
    for (int n = 0; n < 2; ++n) {
      const int c = cc[n], ch16 = c >> 3;
      #pragma unroll
      for (int reg = 0; reg < 4; ++reg) {
        const int j = g * 4 + reg;  // edge row (D layout: row = 4*(lane>>4)+reg)
        s_m1[j * HID + ((ch16 ^ j) * 8) + (c & 7)] = (bf16_t)fmaxf(m1[n][reg], 0.f);
      }
    }
    __syncthreads();

    // ---- msg layer 2 + masked-mean aggregation (cnt == 16 for all v>=1) ----
    f32x4 m2[2];
    #pragma unroll
    for (int n = 0; n < 2; ++n) { m2[n][0]=bs_m2[n]; m2[n][1]=bs_m2[n]; m2[n][2]=bs_m2[n]; m2[n][3]=bs_m2[n]; }
    #pragma unroll
    for (int kk = 0; kk < 4; ++kk) {
      const int phys = (kk * 4 + g) ^ r;
      const bf16x8 a = *(const bf16x8*)(s_m1 + r * HID + phys * 8);
      #pragma unroll
      for (int n = 0; n < 2; ++n) {
        m2[n] = mfma16(a, wm2h[n][kk], m2[n]);
        m2[n] = mfma16(a, wm2l[n][kk], m2[n]);
      }
    }
    #pragma unroll
    for (int n = 0; n < 2; ++n) {
      float s = fmaxf(m2[n][0],0.f)+fmaxf(m2[n][1],0.f)+fmaxf(m2[n][2],0.f)+fmaxf(m2[n][3],0.f);
      s += __shfl_xor(s, 16, 64);
      s += __shfl_xor(s, 32, 64);
      if (lane < 16) s_agg[cc[n]] = s * 0.0625f;
    }
    __syncthreads();

    // ---- update layer 1: cat = [h0_v | agg] (all 16 A-rows identical) ----
    f32x4 u1[2];
    #pragma unroll
    for (int n = 0; n < 2; ++n) { u1[n][0]=bs_u1[n]; u1[n][1]=bs_u1[n]; u1[n][2]=bs_u1[n]; u1[n][3]=bs_u1[n]; }
    #pragma unroll
    for (int kk = 0; kk < 8; ++kk) {
      bf16x8 Ah, Al;
      #pragma unroll
      for (int i = 0; i < 8; ++i) {
        const float f = (kk < 4) ? hv[kk * 8 + i] : s_agg[(kk - 4) * 32 + g * 8 + i];
        const bf16_t fh = (bf16_t)f;
        Ah[i] = fh; Al[i] = (bf16_t)(f - (float)fh);
      }
      #pragma unroll
      for (int n = 0; n < 2; ++n) {
        u1[n] = mfma16(Ah, wu1h[n][kk], u1[n]);
        u1[n] = mfma16(Ah, wu1l[n][kk], u1[n]);
        u1[n] = mfma16(Al, wu1h[n][kk], u1[n]);
      }
    }
    if (lane < 16) {
      s_u1[cc[0]] = fmaxf(u1[0][0], 0.f);
      s_u1[cc[1]] = fmaxf(u1[1][0], 0.f);
    }
    __syncthreads();

    // ---- update layer 2 -> h[v] ----
    f32x4 u2[2];
    #pragma unroll
    for (int n = 0; n < 2; ++n) { u2[n][0]=bs_u2[n]; u2[n][1]=bs_u2[n]; u2[n][2]=bs_u2[n]; u2[n][3]=bs_u2[n]; }
    #pragma unroll
    for (int kk = 0; kk < 4; ++kk) {
      bf16x8 Ah, Al;
      #pragma unroll
      for (int i = 0; i < 8; ++i) {
        const float f = s_u1[kk * 32 + g * 8 + i];
        const bf16_t fh = (bf16_t)f;
        Ah[i] = fh; Al[i] = (bf16_t)(f - (float)fh);
      }
      #pragma unroll
      for (int n = 0; n < 2; ++n) {
        u2[n] = mfma16(Ah, wu2h[n][kk], u2[n]);
        u2[n] = mfma16(Ah, wu2l[n][kk], u2[n]);
        u2[n] = mfma16(Al, wu2h[n][kk], u2[n]);
      }
    }
    if (lane < 16) {  // D row 0 (all rows identical); publish via coherence point
      __hip_atomic_store(&h[(size_t)v * HID + cc[0]], fmaxf(u2[0][0], 0.f),
                         __ATOMIC_RELAXED, __HIP_MEMORY_SCOPE_AGENT);
      __hip_atomic_store(&h[(size_t)v * HID + cc[1]], fmaxf(u2[1][0], 0.f),
                         __ATOMIC_RELAXED, __HIP_MEMORY_SCOPE_AGENT);
    }
    __syncthreads();  // drains all waves' stores (vmcnt(0) before s_barrier)
    if (tid == 0)
      __hip_atomic_store(&flags[v], 1, __ATOMIC_RELEASE, __HIP_MEMORY_SCOPE_AGENT);
  }
}

extern "C" void kernel_launch(void* const* d_in, const int* in_sizes, int n_in,
                              void* d_out, int out_size, void* d_ws, size_t ws_size,
                              hipStream_t stream) {
  const float* x    = (const float*)d_in[0];
  const int*   ei   = (const int*)  d_in[1];   // [2, E] int32; row 0 = src (dst is regular)
  const float* attr = (const float*)d_in[2];
  const float* Wp   = (const float*)d_in[3];
  const float* bp   = (const float*)d_in[4];
  const float* Wm1  = (const float*)d_in[5];
  const float* bm1  = (const float*)d_in[6];
  const float* Wm2  = (const float*)d_in[7];
  const float* bm2  = (const float*)d_in[8];
  const float* Wu1  = (const float*)d_in[9];
  const float* bu1  = (const float*)d_in[10];
  const float* Wu2  = (const float*)d_in[11];
  const float* bu2  = (const float*)d_in[12];
  float* h   = (float*)d_out;   // h state lives directly in d_out
  int* flags = (int*)d_ws;      // NN ints of scratch

  k_h0<<<NN / 8, 128, 0, stream>>>(x, Wp, bp, h, flags);
  k_dag<<<NBLK, 256, 0, stream>>>(ei, attr, Wm1, bm1, Wm2, bm2,
                                  Wu1, bu1, Wu2, bu2, h, flags);
}

// Round 2
// 1343.576 us; speedup vs baseline: 2.4720x; 2.4720x over previous
//
#include <hip/hip_runtime.h>

#define NN   8192
#define DEG  16
#define HID  128
#define IND  128
#define ED   8
#define NBLK 256

typedef __bf16 bf16_t;
typedef __bf16 bf16x8 __attribute__((ext_vector_type(8)));
typedef float  f32x4  __attribute__((ext_vector_type(4)));
typedef unsigned long long u64;

static __device__ __forceinline__ f32x4 mfma16(bf16x8 a, bf16x8 b, f32x4 c) {
  return __builtin_amdgcn_mfma_f32_16x16x32_bf16(a, b, c, 0, 0, 0);
}

// ---------------- kernel 1: h0 = x @ Wp + bp ; init flags ----------------
__global__ __launch_bounds__(128) void k_h0(const float* __restrict__ x,
                                            const float* __restrict__ Wp,
                                            const float* __restrict__ bp,
                                            float* __restrict__ h,
                                            int* __restrict__ flags, int fs) {
  __shared__ float sx[8][IND];
  const int t  = threadIdx.x;      // 0..127 = output channel
  const int vb = blockIdx.x * 8;   // 8 nodes per block
  #pragma unroll
  for (int rr = 0; rr < 8; ++rr) sx[rr][t] = x[(size_t)(vb + rr) * IND + t];
  __syncthreads();
  float acc[8];
  const float bias = bp[t];
  #pragma unroll
  for (int rr = 0; rr < 8; ++rr) acc[rr] = bias;
  for (int k = 0; k < IND; ++k) {
    const float w = Wp[k * HID + t];
    #pragma unroll
    for (int rr = 0; rr < 8; ++rr) acc[rr] += sx[rr][k] * w;
  }
  #pragma unroll
  for (int rr = 0; rr < 8; ++rr) h[(size_t)(vb + rr) * HID + t] = acc[rr];
  // flag word per node: 4 wave-bits; node 0 starts fully "done"
  if (t < 8) flags[(vb + t) * fs] = (vb + t == 0) ? 0xF : 0;
}

// ---------------- kernel 2: persistent DAG executor ----------------
// 256 blocks (1/CU, co-resident), 4 waves/block, each wave owns two 16-ch
// output tiles of every layer; weights register-resident (bf16 hi/lo split).
// Sync: RELAXED spin on padded flag words (no per-iteration buffer_inv);
// per-wave release fetch_or publish BEFORE the block-alignment barrier.
#define LOAD_WFRAGS(W, KROWS, NKK, ARRH, ARRL)                                \
  _Pragma("unroll")                                                           \
  for (int n = 0; n < 2; ++n) {                                               \
    _Pragma("unroll")                                                         \
    for (int kk = 0; kk < NKK; ++kk) {                                        \
      _Pragma("unroll")                                                       \
      for (int i = 0; i < 8; ++i) {                                           \
        const int k = kk * 32 + g * 8 + i;                                    \
        const float w = (k < KROWS) ? W[k * HID + cc[n]] : 0.f;               \
        const bf16_t wh = (bf16_t)w;                                          \
        ARRH[n][kk][i] = wh;                                                  \
        ARRL[n][kk][i] = (bf16_t)(w - (float)wh);                             \
      }                                                                       \
    }                                                                         \
  }

__global__ __launch_bounds__(256, 1) void k_dag(
    const int* __restrict__ ei, const float* __restrict__ attr,
    const float* __restrict__ Wm1, const float* __restrict__ bm1,
    const float* __restrict__ Wm2, const float* __restrict__ bm2,
    const float* __restrict__ Wu1, const float* __restrict__ bu1,
    const float* __restrict__ Wu2, const float* __restrict__ bu2,
    float* __restrict__ h, int* __restrict__ flags, int fs) {
  const int tid  = threadIdx.x;
  const int lane = tid & 63;
  const int g    = lane >> 4;   // 16-lane group: k-block for A/B operands
  const int r    = lane & 15;   // A-row / B-col within tile
  const int wid  = tid >> 6;    // wave 0..3

  __shared__ bf16_t s_m1[16 * HID];   // msg1 activations, chunk-XOR swizzled
  __shared__ float  s_agg[HID];
  __shared__ float  s_u1[HID];

  int cc[2];
  cc[0] = (wid * 2 + 0) * 16 + r;
  cc[1] = (wid * 2 + 1) * 16 + r;

  // ---- register-resident weight fragments (hi/lo bf16 split) ----
  bf16x8 wm1h[2][5], wm1l[2][5], wm2h[2][4], wm2l[2][4];
  bf16x8 wu1h[2][8], wu1l[2][8], wu2h[2][4], wu2l[2][4];
  LOAD_WFRAGS(Wm1, 136, 5, wm1h, wm1l)   // rows 0..127 = h, 128..135 = attr
  LOAD_WFRAGS(Wm2, 128, 4, wm2h, wm2l)
  LOAD_WFRAGS(Wu1, 256, 8, wu1h, wu1l)
  LOAD_WFRAGS(Wu2, 128, 4, wu2h, wu2l)
  float bs_m1[2], bs_m2[2], bs_u1[2], bs_u2[2];
  #pragma unroll
  for (int n = 0; n < 2; ++n) {
    bs_m1[n] = bm1[cc[n]]; bs_m2[n] = bm2[cc[n]];
    bs_u1[n] = bu1[cc[n]]; bs_u2[n] = bu2[cc[n]];
  }

  const int v0 = 1 + (int)blockIdx.x;
  // edge list for the first node (register-carried; refreshed each iteration)
  int s_cur = (v0 < NN) ? ei[(v0 - 1) * DEG + r] : 0;

  for (int v = v0; v < NN; v += NBLK) {
    // ---- prefetch next iteration's edge list (off-chain) ----
    const int vn = (v + NBLK < NN) ? v + NBLK : v;
    const int s_nxt = ei[(vn - 1) * DEG + r];

    // ---- off-chain loads issued before the spin: own h0 row + attr ----
    float hv[32];
    {
      const float* hvp = h + (size_t)v * HID + g * 8;
      #pragma unroll
      for (int kk = 0; kk < 4; ++kk) {
        const f32x4 p0 = *(const f32x4*)(hvp + kk * 32);
        const f32x4 p1 = *(const f32x4*)(hvp + kk * 32 + 4);
        #pragma unroll
        for (int i = 0; i < 4; ++i) { hv[kk*8 + i] = p0[i]; hv[kk*8 + 4 + i] = p1[i]; }
      }
    }
    f32x4 at0 = {0.f,0.f,0.f,0.f}, at1 = {0.f,0.f,0.f,0.f};
    if (g == 0) {
      const f32x4* ap = (const f32x4*)(attr + ((size_t)(v - 1) * DEG + r) * ED);
      at0 = ap[0]; at1 = ap[1];
    }

    // ---- RELAXED spin until this lane's predecessor is fully published ----
    {
      const int* fp = flags + s_cur * fs;
      int fw = __hip_atomic_load(fp, __ATOMIC_RELAXED, __HIP_MEMORY_SCOPE_AGENT);
      int guard = 0;
      while (fw != 0xF && ++guard < (1 << 15)) {   // fail-safe: never hangs
        __builtin_amdgcn_s_sleep(1);
        fw = __hip_atomic_load(fp, __ATOMIC_RELAXED, __HIP_MEMORY_SCOPE_AGENT);
      }
    }
    asm volatile("" ::: "memory");  // compile-time order: gathers stay below

    // ---- gather A fragments: pred rows (hi/lo, via MALL) + attr ----
    bf16x8 ah[5], al[5];
    {
      const u64* hp = (const u64*)(h + (size_t)s_cur * HID) + g * 4;
      #pragma unroll
      for (int kk = 0; kk < 4; ++kk) {
        u64 q[4];
        #pragma unroll
        for (int u = 0; u < 4; ++u)
          q[u] = __hip_atomic_load(hp + kk * 16 + u, __ATOMIC_RELAXED,
                                   __HIP_MEMORY_SCOPE_AGENT);
        #pragma unroll
        for (int u = 0; u < 4; ++u) {
          #pragma unroll
          for (int b = 0; b < 2; ++b) {
            const float f = __uint_as_float((unsigned)(q[u] >> (32 * b)));
            const bf16_t fh = (bf16_t)f;
            ah[kk][u * 2 + b] = fh;
            al[kk][u * 2 + b] = (bf16_t)(f - (float)fh);
          }
        }
      }
      #pragma unroll
      for (int i = 0; i < 4; ++i) {
        ah[4][i]     = (bf16_t)at0[i];   // zeros for g!=0
        ah[4][4 + i] = (bf16_t)at1[i];
        al[4][i] = (bf16_t)0.f; al[4][4 + i] = (bf16_t)0.f;
      }
    }

    // ---- msg layer 1 ----
    f32x4 m1[2];
    #pragma unroll
    for (int n = 0; n < 2; ++n) { m1[n][0]=bs_m1[n]; m1[n][1]=bs_m1[n]; m1[n][2]=bs_m1[n]; m1[n][3]=bs_m1[n]; }
    #pragma unroll
    for (int kk = 0; kk < 4; ++kk) {
      #pragma unroll
      for (int n = 0; n < 2; ++n) {
        m1[n] = mfma16(ah[kk], wm1h[n][kk], m1[n]);
        m1[n] = mfma16(ah[kk], wm1l[n][kk], m1[n]);
        m1[n] = mfma16(al[kk], wm1h[n][kk], m1[n]);
      }
    }
    #pragma unroll
    for (int n = 0; n < 2; ++n) {     // attr k-step
      m1[n] = mfma16(ah[4], wm1h[n][4], m1[n]);
      m1[n] = mfma16(ah[4], wm1l[n][4], m1[n]);
    }
    // relu -> bf16 -> LDS with chunk-XOR swizzle (conflict-free b128 reads)
    #pragma unroll
    for (int n = 0; n < 2; ++n) {
      const int c = cc[n], ch16 = c >> 3;
      #pragma unroll
      for (int reg = 0; reg < 4; ++reg) {
        const int j = g * 4 + reg;  // edge row (D layout: row = 4*(lane>>4)+reg)
        s_m1[j * HID + ((ch16 ^ j) * 8) + (c & 7)] = (bf16_t)fmaxf(m1[n][reg], 0.f);
      }
    }
    __syncthreads();

    // ---- msg layer 2 + mean aggregation (cnt == 16 for all v>=1) ----
    f32x4 m2[2];
    #pragma unroll
    for (int n = 0; n < 2; ++n) { m2[n][0]=bs_m2[n]; m2[n][1]=bs_m2[n]; m2[n][2]=bs_m2[n]; m2[n][3]=bs_m2[n]; }
    #pragma unroll
    for (int kk = 0; kk < 4; ++kk) {
      const int phys = (kk * 4 + g) ^ r;
      const bf16x8 a = *(const bf16x8*)(s_m1 + r * HID + phys * 8);
      #pragma unroll
      for (int n = 0; n < 2; ++n) {
        m2[n] = mfma16(a, wm2h[n][kk], m2[n]);
        m2[n] = mfma16(a, wm2l[n][kk], m2[n]);
      }
    }
    #pragma unroll
    for (int n = 0; n < 2; ++n) {
      float s = fmaxf(m2[n][0],0.f)+fmaxf(m2[n][1],0.f)+fmaxf(m2[n][2],0.f)+fmaxf(m2[n][3],0.f);
      s += __shfl_xor(s, 16, 64);
      s += __shfl_xor(s, 32, 64);
      if (lane < 16) s_agg[cc[n]] = s * 0.0625f;
    }
    __syncthreads();

    // ---- update layer 1: cat = [h0_v | agg] (all 16 A-rows identical) ----
    f32x4 u1[2];
    #pragma unroll
    for (int n = 0; n < 2; ++n) { u1[n][0]=bs_u1[n]; u1[n][1]=bs_u1[n]; u1[n][2]=bs_u1[n]; u1[n][3]=bs_u1[n]; }
    #pragma unroll
    for (int kk = 0; kk < 8; ++kk) {
      bf16x8 Ah, Al;
      #pragma unroll
      for (int i = 0; i < 8; ++i) {
        const float f = (kk < 4) ? hv[kk * 8 + i] : s_agg[(kk - 4) * 32 + g * 8 + i];
        const bf16_t fh = (bf16_t)f;
        Ah[i] = fh; Al[i] = (bf16_t)(f - (float)fh);
      }
      #pragma unroll
      for (int n = 0; n < 2; ++n) {
        u1[n] = mfma16(Ah, wu1h[n][kk], u1[n]);
        u1[n] = mfma16(Ah, wu1l[n][kk], u1[n]);
        u1[n] = mfma16(Al, wu1h[n][kk], u1[n]);
      }
    }
    if (lane < 16) {
      s_u1[cc[0]] = fmaxf(u1[0][0], 0.f);
      s_u1[cc[1]] = fmaxf(u1[1][0], 0.f);
    }
    __syncthreads();

    // ---- update layer 2 -> h[v] ----
    f32x4 u2[2];
    #pragma unroll
    for (int n = 0; n < 2; ++n) { u2[n][0]=bs_u2[n]; u2[n][1]=bs_u2[n]; u2[n][2]=bs_u2[n]; u2[n][3]=bs_u2[n]; }
    #pragma unroll
    for (int kk = 0; kk < 4; ++kk) {
      bf16x8 Ah, Al;
      #pragma unroll
      for (int i = 0; i < 8; ++i) {
        const float f = s_u1[kk * 32 + g * 8 + i];
        const bf16_t fh = (bf16_t)f;
        Ah[i] = fh; Al[i] = (bf16_t)(f - (float)fh);
      }
      #pragma unroll
      for (int n = 0; n < 2; ++n) {
        u2[n] = mfma16(Ah, wu2h[n][kk], u2[n]);
        u2[n] = mfma16(Ah, wu2l[n][kk], u2[n]);
        u2[n] = mfma16(Al, wu2h[n][kk], u2[n]);
      }
    }
    if (lane < 16) {  // D row 0 (all rows identical); write-through to MALL
      __hip_atomic_store(&h[(size_t)v * HID + cc[0]], fmaxf(u2[0][0], 0.f),
                         __ATOMIC_RELAXED, __HIP_MEMORY_SCOPE_AGENT);
      __hip_atomic_store(&h[(size_t)v * HID + cc[1]], fmaxf(u2[1][0], 0.f),
                         __ATOMIC_RELAXED, __HIP_MEMORY_SCOPE_AGENT);
    }
    // per-wave publish: release-OR this wave's bit (drains wave's stores first)
    if (lane == 0)
      __hip_atomic_fetch_or(&flags[v * fs], 1 << wid, __ATOMIC_RELEASE,
                            __HIP_MEMORY_SCOPE_AGENT);
    s_cur = s_nxt;
    __syncthreads();  // alignment barrier: waves must not skew across iters
  }
}

extern "C" void kernel_launch(void* const* d_in, const int* in_sizes, int n_in,
                              void* d_out, int out_size, void* d_ws, size_t ws_size,
                              hipStream_t stream) {
  const float* x    = (const float*)d_in[0];
  const int*   ei   = (const int*)  d_in[1];   // [2, E] int32; row 0 = src
  const float* attr = (const float*)d_in[2];
  const float* Wp   = (const float*)d_in[3];
  const float* bp   = (const float*)d_in[4];
  const float* Wm1  = (const float*)d_in[5];
  const float* bm1  = (const float*)d_in[6];
  const float* Wm2  = (const float*)d_in[7];
  const float* bm2  = (const float*)d_in[8];
  const float* Wu1  = (const float*)d_in[9];
  const float* bu1  = (const float*)d_in[10];
  const float* Wu2  = (const float*)d_in[11];
  const float* bu2  = (const float*)d_in[12];
  float* h   = (float*)d_out;   // h state lives directly in d_out
  int* flags = (int*)d_ws;

  // pad flag words to one 64B line per node if the workspace allows
  const int fs = (ws_size >= (size_t)NN * 64 + 64) ? 16 : 1;

  k_h0<<<NN / 8, 128, 0, stream>>>(x, Wp, bp, h, flags, fs);
  k_dag<<<NBLK, 256, 0, stream>>>(ei, attr, Wm1, bm1, Wm2, bm2,
                                  Wu1, bu1, Wu2, bu2, h, flags, fs);
}

// Round 3
// 784.770 us; speedup vs baseline: 4.2323x; 1.7121x over previous
//
#include <hip/hip_runtime.h>

#define NN   8192
#define DEG  16
#define HID  128
#define IND  128
#define ED   8
#define NBLK 256

typedef __bf16 bf16_t;
typedef __bf16 bf16x8 __attribute__((ext_vector_type(8)));
typedef float  f32x4  __attribute__((ext_vector_type(4)));
typedef unsigned long long u64;

static __device__ __forceinline__ f32x4 mfma16(bf16x8 a, bf16x8 b, f32x4 c) {
  return __builtin_amdgcn_mfma_f32_16x16x32_bf16(a, b, c, 0, 0, 0);
}

// ---------------- kernel 1: h0 = x @ Wp + bp ; init sync state ----------------
__global__ __launch_bounds__(128) void k_h0(const float* __restrict__ x,
                                            const float* __restrict__ Wp,
                                            const float* __restrict__ bp,
                                            float* __restrict__ h,
                                            unsigned* __restrict__ h2u,
                                            int* __restrict__ flags, int fs,
                                            int sent) {
  __shared__ float sx[8][IND];
  const int t  = threadIdx.x;      // 0..127 = output channel
  const int vb = blockIdx.x * 8;   // 8 nodes per block
  #pragma unroll
  for (int rr = 0; rr < 8; ++rr) sx[rr][t] = x[(size_t)(vb + rr) * IND + t];
  __syncthreads();
  float acc[8];
  const float bias = bp[t];
  #pragma unroll
  for (int rr = 0; rr < 8; ++rr) acc[rr] = bias;
  for (int k = 0; k < IND; ++k) {
    const float w = Wp[k * HID + t];
    #pragma unroll
    for (int rr = 0; rr < 8; ++rr) acc[rr] += sx[rr][k] * w;
  }
  #pragma unroll
  for (int rr = 0; rr < 8; ++rr) h[(size_t)(vb + rr) * HID + t] = acc[rr];
  if (sent) {
    // h2: row 0 = h0 (node 0 is final); rows >=1 = sentinel (sign bit set)
    #pragma unroll
    for (int rr = 0; rr < 8; ++rr)
      h2u[(size_t)(vb + rr) * HID + t] =
          (vb + rr == 0) ? __float_as_uint(acc[rr]) : 0xFFFFFFFFu;
  } else if (t < 8) {
    flags[(vb + t) * fs] = (vb + t == 0) ? 0xF : 0;
  }
}

// ---------------- kernel 2: persistent DAG executor ----------------
// 256 blocks (1/CU, co-resident), 4 waves, each wave owns two 16-ch output
// tiles; weights register-resident (bf16 hi/lo split). SENT mode: consumers
// spin directly on the h2 row (sign-bit sentinel) -- detect==gather, no flag.
#define LOAD_WFRAGS(W, KROWS, NKK, ARRH, ARRL)                                \
  _Pragma("unroll")                                                           \
  for (int n = 0; n < 2; ++n) {                                               \
    _Pragma("unroll")                                                         \
    for (int kk = 0; kk < NKK; ++kk) {                                        \
      _Pragma("unroll")                                                       \
      for (int i = 0; i < 8; ++i) {                                           \
        const int k = kk * 32 + g * 8 + i;                                    \
        const float w = (k < KROWS) ? W[k * HID + cc[n]] : 0.f;               \
        const bf16_t wh = (bf16_t)w;                                          \
        ARRH[n][kk][i] = wh;                                                  \
        ARRL[n][kk][i] = (bf16_t)(w - (float)wh);                             \
      }                                                                       \
    }                                                                         \
  }

#define LOADQ()                                                               \
  _Pragma("unroll")                                                           \
  for (int kk = 0; kk < 4; ++kk) {                                            \
    _Pragma("unroll")                                                         \
    for (int u = 0; u < 4; ++u)                                               \
      q[kk * 4 + u] = __hip_atomic_load(hp + kk * 16 + u, __ATOMIC_RELAXED,   \
                                        __HIP_MEMORY_SCOPE_AGENT);            \
  }

template <bool SENT>
__global__ __launch_bounds__(256, 1) void k_dag(
    const int* __restrict__ ei, const float* __restrict__ attr,
    const float* __restrict__ Wm1, const float* __restrict__ bm1,
    const float* __restrict__ Wm2, const float* __restrict__ bm2,
    const float* __restrict__ Wu1, const float* __restrict__ bu1,
    const float* __restrict__ Wu2, const float* __restrict__ bu2,
    float* __restrict__ h, float* __restrict__ h2,
    int* __restrict__ flags, int fs) {
  const int tid  = threadIdx.x;
  const int lane = tid & 63;
  const int g    = lane >> 4;   // 16-lane group: k-block of A/B operands
  const int r    = lane & 15;   // A-row / B-col within tile
  const int wid  = tid >> 6;    // wave 0..3

  __shared__ bf16_t s_m1[16 * HID];   // msg1 activations, chunk-XOR swizzled
  __shared__ float  s_agg[HID];
  __shared__ float  s_u1[HID];

  int cc[2];
  cc[0] = (wid * 2 + 0) * 16 + r;
  cc[1] = (wid * 2 + 1) * 16 + r;

  // ---- register-resident weight fragments (bf16 hi/lo split) ----
  bf16x8 wm1h[2][5], wm1l[2][5], wm2h[2][4], wm2l[2][4];
  bf16x8 wu1h[2][8], wu1l[2][8], wu2h[2][4], wu2l[2][4];
  LOAD_WFRAGS(Wm1, 136, 5, wm1h, wm1l)   // rows 0..127 = h, 128..135 = attr
  LOAD_WFRAGS(Wm2, 128, 4, wm2h, wm2l)
  LOAD_WFRAGS(Wu1, 256, 8, wu1h, wu1l)
  LOAD_WFRAGS(Wu2, 128, 4, wu2h, wu2l)
  float bs_m1[2], bs_m2[2], bs_u1[2], bs_u2[2];
  #pragma unroll
  for (int n = 0; n < 2; ++n) {
    bs_m1[n] = bm1[cc[n]]; bs_m2[n] = bm2[cc[n]];
    bs_u1[n] = bu1[cc[n]]; bs_u2[n] = bu2[cc[n]];
  }

  const int v0 = 1 + (int)blockIdx.x;
  int s_cur = (v0 < NN) ? ei[(v0 - 1) * DEG + r] : 0;

  for (int v = v0; v < NN; v += NBLK) {
    // ---- off-chain: next edge list, own h0 row -> fragments, attr frag ----
    const int vn = (v + NBLK < NN) ? v + NBLK : v;
    const int s_nxt = ei[(vn - 1) * DEG + r];

    bf16x8 hvh[4], hvl[4];
    {
      const float* hvp = h + (size_t)v * HID + g * 8;
      #pragma unroll
      for (int kk = 0; kk < 4; ++kk) {
        const f32x4 p0 = *(const f32x4*)(hvp + kk * 32);
        const f32x4 p1 = *(const f32x4*)(hvp + kk * 32 + 4);
        #pragma unroll
        for (int i = 0; i < 4; ++i) {
          const float f0 = p0[i], f1 = p1[i];
          const bf16_t f0h = (bf16_t)f0, f1h = (bf16_t)f1;
          hvh[kk][i]     = f0h; hvl[kk][i]     = (bf16_t)(f0 - (float)f0h);
          hvh[kk][4 + i] = f1h; hvl[kk][4 + i] = (bf16_t)(f1 - (float)f1h);
        }
      }
    }
    bf16x8 a4h;
    #pragma unroll
    for (int i = 0; i < 8; ++i) a4h[i] = (bf16_t)0.f;
    if (g == 0) {
      const f32x4* ap = (const f32x4*)(attr + ((size_t)(v - 1) * DEG + r) * ED);
      const f32x4 a0 = ap[0], a1 = ap[1];
      #pragma unroll
      for (int i = 0; i < 4; ++i) {
        a4h[i] = (bf16_t)a0[i]; a4h[4 + i] = (bf16_t)a1[i];
      }
    }

    // ---- sync + gather the 16 predecessor rows ----
    u64 q[16];
    const u64* hp = (const u64*)((SENT ? h2 : h) + (size_t)s_cur * HID) + g * 4;
    if constexpr (SENT) {
      // spin on the data itself: relu'd rows are all sign-clear; sentinel has
      // sign set. src==0 is the h0 row (always ready, may be negative): bypass.
      bool ok = false;
      int guard = 0;
      for (;;) {
        if (!ok) {
          LOADQ();
          u64 m = 0;
          #pragma unroll
          for (int i = 0; i < 16; ++i) m |= q[i];
          ok = (s_cur == 0) || ((m & 0x8000000080000000ull) == 0);
        }
        if (__all(ok)) break;
        if (++guard > (1 << 14)) break;  // fail-safe: wrong answer, never hang
        __builtin_amdgcn_s_sleep(1);
      }
    } else {
      const int* fp = flags + s_cur * fs;
      int fw = __hip_atomic_load(fp, __ATOMIC_RELAXED, __HIP_MEMORY_SCOPE_AGENT);
      int guard = 0;
      while (fw != 0xF && ++guard < (1 << 15)) {
        __builtin_amdgcn_s_sleep(1);
        fw = __hip_atomic_load(fp, __ATOMIC_RELAXED, __HIP_MEMORY_SCOPE_AGENT);
      }
      asm volatile("" ::: "memory");  // gathers stay below the spin
      LOADQ();
    }

    // ---- convert gathered rows to A fragments (hi/lo) ----
    bf16x8 ah[5], al[5];
    #pragma unroll
    for (int kk = 0; kk < 4; ++kk) {
      #pragma unroll
      for (int u = 0; u < 4; ++u) {
        #pragma unroll
        for (int b = 0; b < 2; ++b) {
          const float f = __uint_as_float((unsigned)(q[kk * 4 + u] >> (32 * b)));
          const bf16_t fh = (bf16_t)f;
          ah[kk][u * 2 + b] = fh;
          al[kk][u * 2 + b] = (bf16_t)(f - (float)fh);
        }
      }
    }
    ah[4] = a4h;

    // ---- msg layer 1 (3 parallel accumulator chains) ----
    f32x4 m1[2];
    {
      f32x4 aA[2], aB[2], aC[2];
      #pragma unroll
      for (int n = 0; n < 2; ++n) {
        aA[n][0]=bs_m1[n]; aA[n][1]=bs_m1[n]; aA[n][2]=bs_m1[n]; aA[n][3]=bs_m1[n];
        aB[n][0]=0.f; aB[n][1]=0.f; aB[n][2]=0.f; aB[n][3]=0.f;
        aC[n] = aB[n];
      }
      #pragma unroll
      for (int kk = 0; kk < 4; ++kk) {
        #pragma unroll
        for (int n = 0; n < 2; ++n) {
          aA[n] = mfma16(ah[kk], wm1h[n][kk], aA[n]);
          aB[n] = mfma16(ah[kk], wm1l[n][kk], aB[n]);
          aC[n] = mfma16(al[kk], wm1h[n][kk], aC[n]);
        }
      }
      #pragma unroll
      for (int n = 0; n < 2; ++n) {   // attr k-step
        aA[n] = mfma16(ah[4], wm1h[n][4], aA[n]);
        aB[n] = mfma16(ah[4], wm1l[n][4], aB[n]);
        m1[n] = aA[n] + aB[n] + aC[n];
      }
    }
    // relu -> bf16 -> LDS with chunk-XOR swizzle (conflict-free b128 reads)
    #pragma unroll
    for (int n = 0; n < 2; ++n) {
      const int c = cc[n], ch16 = c >> 3;
      #pragma unroll
      for (int reg = 0; reg < 4; ++reg) {
        const int j = g * 4 + reg;  // edge row (D layout: row = 4*(lane>>4)+reg)
        s_m1[j * HID + ((ch16 ^ j) * 8) + (c & 7)] = (bf16_t)fmaxf(m1[n][reg], 0.f);
      }
    }
    __syncthreads();

    // ---- msg layer 2 + mean aggregation (cnt == 16 for all v>=1) ----
    f32x4 m2[2];
    {
      f32x4 aA[2], aB[2];
      #pragma unroll
      for (int n = 0; n < 2; ++n) {
        aA[n][0]=bs_m2[n]; aA[n][1]=bs_m2[n]; aA[n][2]=bs_m2[n]; aA[n][3]=bs_m2[n];
        aB[n][0]=0.f; aB[n][1]=0.f; aB[n][2]=0.f; aB[n][3]=0.f;
      }
      #pragma unroll
      for (int kk = 0; kk < 4; ++kk) {
        const int phys = (kk * 4 + g) ^ r;
        const bf16x8 a = *(const bf16x8*)(s_m1 + r * HID + phys * 8);
        #pragma unroll
        for (int n = 0; n < 2; ++n) {
          aA[n] = mfma16(a, wm2h[n][kk], aA[n]);
          aB[n] = mfma16(a, wm2l[n][kk], aB[n]);
        }
      }
      #pragma unroll
      for (int n = 0; n < 2; ++n) m2[n] = aA[n] + aB[n];
    }
    #pragma unroll
    for (int n = 0; n < 2; ++n) {
      float s = fmaxf(m2[n][0],0.f)+fmaxf(m2[n][1],0.f)+fmaxf(m2[n][2],0.f)+fmaxf(m2[n][3],0.f);
      s += __shfl_xor(s, 16, 64);
      s += __shfl_xor(s, 32, 64);
      if (lane < 16) s_agg[cc[n]] = s * 0.0625f;
    }
    __syncthreads();

    // ---- update layer 1: cat = [h0_v | agg] (all 16 A-rows identical) ----
    f32x4 u1v[2];
    {
      f32x4 aA[2], aB[2], aC[2];
      #pragma unroll
      for (int n = 0; n < 2; ++n) {
        aA[n][0]=bs_u1[n]; aA[n][1]=bs_u1[n]; aA[n][2]=bs_u1[n]; aA[n][3]=bs_u1[n];
        aB[n][0]=0.f; aB[n][1]=0.f; aB[n][2]=0.f; aB[n][3]=0.f;
        aC[n] = aB[n];
      }
      #pragma unroll
      for (int kk = 0; kk < 8; ++kk) {
        bf16x8 Ah, Al;
        if (kk < 4) { Ah = hvh[kk]; Al = hvl[kk]; }
        else {
          #pragma unroll
          for (int i = 0; i < 8; ++i) {
            const float f = s_agg[(kk - 4) * 32 + g * 8 + i];
            const bf16_t fh = (bf16_t)f;
            Ah[i] = fh; Al[i] = (bf16_t)(f - (float)fh);
          }
        }
        #pragma unroll
        for (int n = 0; n < 2; ++n) {
          aA[n] = mfma16(Ah, wu1h[n][kk], aA[n]);
          aB[n] = mfma16(Ah, wu1l[n][kk], aB[n]);
          aC[n] = mfma16(Al, wu1h[n][kk], aC[n]);
        }
      }
      #pragma unroll
      for (int n = 0; n < 2; ++n) u1v[n] = aA[n] + aB[n] + aC[n];
    }
    if (lane < 16) {
      s_u1[cc[0]] = fmaxf(u1v[0][0], 0.f);
      s_u1[cc[1]] = fmaxf(u1v[1][0], 0.f);
    }
    __syncthreads();

    // ---- update layer 2 -> publish ----
    f32x4 u2v[2];
    {
      f32x4 aA[2], aB[2], aC[2];
      #pragma unroll
      for (int n = 0; n < 2; ++n) {
        aA[n][0]=bs_u2[n]; aA[n][1]=bs_u2[n]; aA[n][2]=bs_u2[n]; aA[n][3]=bs_u2[n];
        aB[n][0]=0.f; aB[n][1]=0.f; aB[n][2]=0.f; aB[n][3]=0.f;
        aC[n] = aB[n];
      }
      #pragma unroll
      for (int kk = 0; kk < 4; ++kk) {
        bf16x8 Ah, Al;
        #pragma unroll
        for (int i = 0; i < 8; ++i) {
          const float f = s_u1[kk * 32 + g * 8 + i];
          const bf16_t fh = (bf16_t)f;
          Ah[i] = fh; Al[i] = (bf16_t)(f - (float)fh);
        }
        #pragma unroll
        for (int n = 0; n < 2; ++n) {
          aA[n] = mfma16(Ah, wu2h[n][kk], aA[n]);
          aB[n] = mfma16(Ah, wu2l[n][kk], aB[n]);
          aC[n] = mfma16(Al, wu2h[n][kk], aC[n]);
        }
      }
      #pragma unroll
      for (int n = 0; n < 2; ++n) u2v[n] = aA[n] + aB[n] + aC[n];
    }
    if (lane < 16) {  // D row 0 (all rows identical)
      const float r0 = fabsf(fmaxf(u2v[0][0], 0.f));  // fabs: kill -0.0 (sign = sentinel)
      const float r1 = fabsf(fmaxf(u2v[1][0], 0.f));
      if constexpr (SENT) {
        h[(size_t)v * HID + cc[0]] = r0;              // final output (cached)
        h[(size_t)v * HID + cc[1]] = r1;
        __hip_atomic_store(&h2[(size_t)v * HID + cc[0]], r0, __ATOMIC_RELAXED,
                           __HIP_MEMORY_SCOPE_AGENT);  // sync channel (MALL)
        __hip_atomic_store(&h2[(size_t)v * HID + cc[1]], r1, __ATOMIC_RELAXED,
                           __HIP_MEMORY_SCOPE_AGENT);
      } else {
        __hip_atomic_store(&h[(size_t)v * HID + cc[0]], r0, __ATOMIC_RELAXED,
                           __HIP_MEMORY_SCOPE_AGENT);
        __hip_atomic_store(&h[(size_t)v * HID + cc[1]], r1, __ATOMIC_RELAXED,
                           __HIP_MEMORY_SCOPE_AGENT);
      }
    }
    if constexpr (!SENT) {
      if (lane == 0)
        __hip_atomic_fetch_or(&flags[v * fs], 1 << wid, __ATOMIC_RELEASE,
                              __HIP_MEMORY_SCOPE_AGENT);
    }
    s_cur = s_nxt;
    __syncthreads();  // alignment barrier: waves must not skew across iters
  }
}

extern "C" void kernel_launch(void* const* d_in, const int* in_sizes, int n_in,
                              void* d_out, int out_size, void* d_ws, size_t ws_size,
                              hipStream_t stream) {
  const float* x    = (const float*)d_in[0];
  const int*   ei   = (const int*)  d_in[1];   // [2, E] int32; row 0 = src
  const float* attr = (const float*)d_in[2];
  const float* Wp   = (const float*)d_in[3];
  const float* bp   = (const float*)d_in[4];
  const float* Wm1  = (const float*)d_in[5];
  const float* bm1  = (const float*)d_in[6];
  const float* Wm2  = (const float*)d_in[7];
  const float* bm2  = (const float*)d_in[8];
  const float* Wu1  = (const float*)d_in[9];
  const float* bu1  = (const float*)d_in[10];
  const float* Wu2  = (const float*)d_in[11];
  const float* bu2  = (const float*)d_in[12];
  float* h = (float*)d_out;   // h state lives directly in d_out

  const size_t h2_bytes = (size_t)NN * HID * sizeof(float);  // 4 MB
  const bool sent = ws_size >= h2_bytes;
  float* h2  = (float*)d_ws;
  int* flags = (int*)d_ws;
  const int fs = sent ? 0 : ((ws_size >= (size_t)NN * 64 + 64) ? 16 : 1);

  k_h0<<<NN / 8, 128, 0, stream>>>(x, Wp, bp, h, (unsigned*)h2, flags, fs,
                                   sent ? 1 : 0);
  if (sent)
    k_dag<true><<<NBLK, 256, 0, stream>>>(ei, attr, Wm1, bm1, Wm2, bm2,
                                          Wu1, bu1, Wu2, bu2, h, h2, flags, fs);
  else
    k_dag<false><<<NBLK, 256, 0, stream>>>(ei, attr, Wm1, bm1, Wm2, bm2,
                                           Wu1, bu1, Wu2, bu2, h, h2, flags, fs);
}

// Round 4
// 724.071 us; speedup vs baseline: 4.5871x; 1.0838x over previous
//
#include <hip/hip_runtime.h>

#define NN   8192
#define DEG  16
#define HID  128
#define IND  128
#define ED   8
#define NBLK 256

typedef __bf16 bf16_t;
typedef __bf16 bf16x8 __attribute__((ext_vector_type(8)));
typedef float  f32x4  __attribute__((ext_vector_type(4)));
typedef unsigned long long u64;

static __device__ __forceinline__ f32x4 mfma16(bf16x8 a, bf16x8 b, f32x4 c) {
  return __builtin_amdgcn_mfma_f32_16x16x32_bf16(a, b, c, 0, 0, 0);
}
static __device__ __forceinline__ unsigned short bfbits(bf16_t x) {
  return __builtin_bit_cast(unsigned short, x);
}
static __device__ __forceinline__ bf16_t bits2bf(unsigned short x) {
  return __builtin_bit_cast(bf16_t, x);
}
// LDS-phase barrier: drain LDS ops only -- global loads/stores stay in flight.
static __device__ __forceinline__ void bar_lds() {
  __builtin_amdgcn_sched_barrier(0);
  asm volatile("s_waitcnt lgkmcnt(0)" ::: "memory");
  __builtin_amdgcn_s_barrier();
  __builtin_amdgcn_sched_barrier(0);
}
// alignment barrier: no waitcnt at all (publish stores keep flying)
static __device__ __forceinline__ void bar_align() {
  __builtin_amdgcn_sched_barrier(0);
  __builtin_amdgcn_s_barrier();
  __builtin_amdgcn_sched_barrier(0);
}

// ---------------- kernel 1: h0 = x @ Wp + bp ; init sync state ----------------
__global__ __launch_bounds__(128) void k_h0(const float* __restrict__ x,
                                            const float* __restrict__ Wp,
                                            const float* __restrict__ bp,
                                            float* __restrict__ h,
                                            unsigned* __restrict__ h2u,
                                            int* __restrict__ flags, int fs,
                                            int sent) {
  __shared__ float sx[8][IND];
  const int t  = threadIdx.x;      // 0..127 = output channel
  const int vb = blockIdx.x * 8;   // 8 nodes per block
  #pragma unroll
  for (int rr = 0; rr < 8; ++rr) sx[rr][t] = x[(size_t)(vb + rr) * IND + t];
  __syncthreads();
  float acc[8];
  const float bias = bp[t];
  #pragma unroll
  for (int rr = 0; rr < 8; ++rr) acc[rr] = bias;
  for (int k = 0; k < IND; ++k) {
    const float w = Wp[k * HID + t];
    #pragma unroll
    for (int rr = 0; rr < 8; ++rr) acc[rr] += sx[rr][k] * w;
  }
  #pragma unroll
  for (int rr = 0; rr < 8; ++rr) h[(size_t)(vb + rr) * HID + t] = acc[rr];
  if (sent) {
    // h2: row 0 = packed hi/lo of h0 (node 0 final); rows >=1 = sentinel
    #pragma unroll
    for (int rr = 0; rr < 8; ++rr) {
      unsigned val = 0xFFFFFFFFu;
      if (vb + rr == 0) {
        const float f = acc[rr];
        const bf16_t fh = (bf16_t)f;
        const bf16_t fl = (bf16_t)(f - (float)fh);
        val = ((unsigned)bfbits(fh) << 16) | (unsigned)bfbits(fl);
      }
      h2u[(size_t)(vb + rr) * HID + t] = val;
    }
  } else if (t < 8) {
    flags[(vb + t) * fs] = (vb + t == 0) ? 0xF : 0;
  }
}

// ---------------- kernel 2: persistent DAG executor ----------------
// 256 blocks (1/CU, co-resident), 4 waves, each wave owns two 16-ch output
// tiles; weights register-resident (bf16 hi/lo split). SENT mode: consumers
// spin on the packed h2 row (bit31 sentinel) -- detect==gather, data arrives
// pre-split so no convert chain on the critical path.
#define LOAD_WFRAGS(W, KROWS, NKK, ARRH, ARRL)                                \
  _Pragma("unroll")                                                           \
  for (int n = 0; n < 2; ++n) {                                               \
    _Pragma("unroll")                                                         \
    for (int kk = 0; kk < NKK; ++kk) {                                        \
      _Pragma("unroll")                                                       \
      for (int i = 0; i < 8; ++i) {                                           \
        const int k = kk * 32 + g * 8 + i;                                    \
        const float w = (k < KROWS) ? W[k * HID + cc[n]] : 0.f;               \
        const bf16_t wh = (bf16_t)w;                                          \
        ARRH[n][kk][i] = wh;                                                  \
        ARRL[n][kk][i] = (bf16_t)(w - (float)wh);                             \
      }                                                                       \
    }                                                                         \
  }

#define LOADQ()                                                               \
  _Pragma("unroll")                                                           \
  for (int kk = 0; kk < 4; ++kk) {                                            \
    _Pragma("unroll")                                                         \
    for (int u = 0; u < 4; ++u)                                               \
      q[kk * 4 + u] = __hip_atomic_load(hp + kk * 16 + u, __ATOMIC_RELAXED,   \
                                        __HIP_MEMORY_SCOPE_AGENT);            \
  }

template <bool SENT>
__global__ __launch_bounds__(256, 1) void k_dag(
    const int* __restrict__ ei, const float* __restrict__ attr,
    const float* __restrict__ Wm1, const float* __restrict__ bm1,
    const float* __restrict__ Wm2, const float* __restrict__ bm2,
    const float* __restrict__ Wu1, const float* __restrict__ bu1,
    const float* __restrict__ Wu2, const float* __restrict__ bu2,
    float* __restrict__ h, unsigned* __restrict__ h2u,
    int* __restrict__ flags, int fs) {
  const int tid  = threadIdx.x;
  const int lane = tid & 63;
  const int g    = lane >> 4;   // 16-lane group: k-block of A/B operands
  const int r    = lane & 15;   // A-row / B-col within tile
  const int wid  = tid >> 6;    // wave 0..3

  __shared__ bf16_t s_m1[16 * HID];   // msg1 activations, chunk-XOR swizzled
  __shared__ float  s_agg[HID];
  __shared__ float  s_u1[HID];

  int cc[2];
  cc[0] = (wid * 2 + 0) * 16 + r;
  cc[1] = (wid * 2 + 1) * 16 + r;

  // ---- register-resident weight fragments (bf16 hi/lo split) ----
  bf16x8 wm1h[2][5], wm1l[2][5], wm2h[2][4], wm2l[2][4];
  bf16x8 wu1h[2][8], wu1l[2][8], wu2h[2][4], wu2l[2][4];
  LOAD_WFRAGS(Wm1, 136, 5, wm1h, wm1l)   // rows 0..127 = h, 128..135 = attr
  LOAD_WFRAGS(Wm2, 128, 4, wm2h, wm2l)
  LOAD_WFRAGS(Wu1, 256, 8, wu1h, wu1l)
  LOAD_WFRAGS(Wu2, 128, 4, wu2h, wu2l)
  float bs_m1[2], bs_m2[2], bs_u1[2], bs_u2[2];
  #pragma unroll
  for (int n = 0; n < 2; ++n) {
    bs_m1[n] = bm1[cc[n]]; bs_m2[n] = bm2[cc[n]];
    bs_u1[n] = bu1[cc[n]]; bs_u2[n] = bu2[cc[n]];
  }

  const int v0 = 1 + (int)blockIdx.x;
  int s_cur = (v0 < NN) ? ei[(v0 - 1) * DEG + r] : 0;

  for (int v = v0; v < NN; v += NBLK) {
    // ---- off-chain: next edge list, own h0 row -> fragments, attr frag ----
    const int vn = (v + NBLK < NN) ? v + NBLK : v;
    const int s_nxt = ei[(vn - 1) * DEG + r];

    bf16x8 hvh[4], hvl[4];
    {
      const float* hvp = h + (size_t)v * HID + g * 8;
      #pragma unroll
      for (int kk = 0; kk < 4; ++kk) {
        const f32x4 p0 = *(const f32x4*)(hvp + kk * 32);
        const f32x4 p1 = *(const f32x4*)(hvp + kk * 32 + 4);
        #pragma unroll
        for (int i = 0; i < 4; ++i) {
          const float f0 = p0[i], f1 = p1[i];
          const bf16_t f0h = (bf16_t)f0, f1h = (bf16_t)f1;
          hvh[kk][i]     = f0h; hvl[kk][i]     = (bf16_t)(f0 - (float)f0h);
          hvh[kk][4 + i] = f1h; hvl[kk][4 + i] = (bf16_t)(f1 - (float)f1h);
        }
      }
    }
    bf16x8 a4h;
    #pragma unroll
    for (int i = 0; i < 8; ++i) a4h[i] = (bf16_t)0.f;
    if (g == 0) {
      const f32x4* ap = (const f32x4*)(attr + ((size_t)(v - 1) * DEG + r) * ED);
      const f32x4 a0 = ap[0], a1 = ap[1];
      #pragma unroll
      for (int i = 0; i < 4; ++i) {
        a4h[i] = (bf16_t)a0[i]; a4h[4 + i] = (bf16_t)a1[i];
      }
    }

    // ---- issue first poll/gather loads ----
    u64 q[16];
    const u64* hp =
        (const u64*)((SENT ? (const void*)h2u : (const void*)h)) +
        (size_t)s_cur * (HID / 2) + g * 4;
    LOADQ();

    // ---- u1 h0_v-half: fully off-chain (own data + weights only) ----
    // overlaps the in-flight poll loads above
    f32x4 uA[2], uB[2], uC[2];
    #pragma unroll
    for (int n = 0; n < 2; ++n) {
      uA[n][0]=bs_u1[n]; uA[n][1]=bs_u1[n]; uA[n][2]=bs_u1[n]; uA[n][3]=bs_u1[n];
      uB[n][0]=0.f; uB[n][1]=0.f; uB[n][2]=0.f; uB[n][3]=0.f;
      uC[n] = uB[n];
    }
    #pragma unroll
    for (int kk = 0; kk < 4; ++kk) {
      #pragma unroll
      for (int n = 0; n < 2; ++n) {
        uA[n] = mfma16(hvh[kk], wu1h[n][kk], uA[n]);
        uB[n] = mfma16(hvh[kk], wu1l[n][kk], uB[n]);
        uC[n] = mfma16(hvl[kk], wu1h[n][kk], uC[n]);
      }
    }

    // ---- spin: data IS the sync (bit31 of each packed u32 = sentinel) ----
    if constexpr (SENT) {
      bool ok = false;
      int guard = 0;
      for (;;) {
        if (!ok) {
          u64 m = 0;
          #pragma unroll
          for (int i = 0; i < 16; ++i) m |= q[i];
          ok = (s_cur == 0) || ((m & 0x8000000080000000ull) == 0);
        }
        if (__all(ok)) break;
        if (++guard > (1 << 13)) break;  // fail-safe: wrong answer, never hang
        if (!ok) LOADQ();
      }
    } else {
      const int* fp = flags + s_cur * fs;
      int fw = __hip_atomic_load(fp, __ATOMIC_RELAXED, __HIP_MEMORY_SCOPE_AGENT);
      int guard = 0;
      while (fw != 0xF && ++guard < (1 << 15)) {
        __builtin_amdgcn_s_sleep(1);
        fw = __hip_atomic_load(fp, __ATOMIC_RELAXED, __HIP_MEMORY_SCOPE_AGENT);
      }
      asm volatile("" ::: "memory");  // gathers stay below the spin
      LOADQ();
    }

    // ---- A fragments: SENT = pure bit-split; fallback = f32 convert ----
    bf16x8 ah[5], al[5];
    #pragma unroll
    for (int kk = 0; kk < 4; ++kk) {
      #pragma unroll
      for (int u = 0; u < 4; ++u) {
        #pragma unroll
        for (int b = 0; b < 2; ++b) {
          const unsigned w = (unsigned)(q[kk * 4 + u] >> (32 * b));
          if constexpr (SENT) {
            ah[kk][u * 2 + b] = bits2bf((unsigned short)(w >> 16));
            al[kk][u * 2 + b] = bits2bf((unsigned short)(w & 0xFFFFu));
          } else {
            const float f = __uint_as_float(w);
            const bf16_t fh = (bf16_t)f;
            ah[kk][u * 2 + b] = fh;
            al[kk][u * 2 + b] = (bf16_t)(f - (float)fh);
          }
        }
      }
    }
    ah[4] = a4h;

    // ---- msg layer 1 (3 parallel accumulator chains) ----
    f32x4 m1[2];
    {
      f32x4 aA[2], aB[2], aC[2];
      #pragma unroll
      for (int n = 0; n < 2; ++n) {
        aA[n][0]=bs_m1[n]; aA[n][1]=bs_m1[n]; aA[n][2]=bs_m1[n]; aA[n][3]=bs_m1[n];
        aB[n][0]=0.f; aB[n][1]=0.f; aB[n][2]=0.f; aB[n][3]=0.f;
        aC[n] = aB[n];
      }
      #pragma unroll
      for (int kk = 0; kk < 4; ++kk) {
        #pragma unroll
        for (int n = 0; n < 2; ++n) {
          aA[n] = mfma16(ah[kk], wm1h[n][kk], aA[n]);
          aB[n] = mfma16(ah[kk], wm1l[n][kk], aB[n]);
          aC[n] = mfma16(al[kk], wm1h[n][kk], aC[n]);
        }
      }
      #pragma unroll
      for (int n = 0; n < 2; ++n) {   // attr k-step
        aA[n] = mfma16(ah[4], wm1h[n][4], aA[n]);
        aB[n] = mfma16(ah[4], wm1l[n][4], aB[n]);
        m1[n] = aA[n] + aB[n] + aC[n];
      }
    }
    // relu -> bf16 -> LDS with chunk-XOR swizzle (conflict-free b128 reads)
    #pragma unroll
    for (int n = 0; n < 2; ++n) {
      const int c = cc[n], ch16 = c >> 3;
      #pragma unroll
      for (int reg = 0; reg < 4; ++reg) {
        const int j = g * 4 + reg;  // edge row (D layout: row = 4*(lane>>4)+reg)
        s_m1[j * HID + ((ch16 ^ j) * 8) + (c & 7)] = (bf16_t)fmaxf(m1[n][reg], 0.f);
      }
    }
    if constexpr (SENT) bar_lds(); else __syncthreads();

    // ---- msg layer 2 + mean aggregation (cnt == 16 for all v>=1) ----
    f32x4 m2[2];
    {
      f32x4 aA[2], aB[2];
      #pragma unroll
      for (int n = 0; n < 2; ++n) {
        aA[n][0]=bs_m2[n]; aA[n][1]=bs_m2[n]; aA[n][2]=bs_m2[n]; aA[n][3]=bs_m2[n];
        aB[n][0]=0.f; aB[n][1]=0.f; aB[n][2]=0.f; aB[n][3]=0.f;
      }
      #pragma unroll
      for (int kk = 0; kk < 4; ++kk) {
        const int phys = (kk * 4 + g) ^ r;
        const bf16x8 a = *(const bf16x8*)(s_m1 + r * HID + phys * 8);
        #pragma unroll
        for (int n = 0; n < 2; ++n) {
          aA[n] = mfma16(a, wm2h[n][kk], aA[n]);
          aB[n] = mfma16(a, wm2l[n][kk], aB[n]);
        }
      }
      #pragma unroll
      for (int n = 0; n < 2; ++n) m2[n] = aA[n] + aB[n];
    }
    #pragma unroll
    for (int n = 0; n < 2; ++n) {
      float s = fmaxf(m2[n][0],0.f)+fmaxf(m2[n][1],0.f)+fmaxf(m2[n][2],0.f)+fmaxf(m2[n][3],0.f);
      s += __shfl_xor(s, 16, 64);
      s += __shfl_xor(s, 32, 64);
      if (lane < 16) s_agg[cc[n]] = s * 0.0625f;
    }
    if constexpr (SENT) bar_lds(); else __syncthreads();

    // ---- update layer 1, agg-half only (h0-half precomputed) ----
    f32x4 u1v[2];
    #pragma unroll
    for (int kk = 4; kk < 8; ++kk) {
      bf16x8 Ah, Al;
      #pragma unroll
      for (int i = 0; i < 8; ++i) {
        const float f = s_agg[(kk - 4) * 32 + g * 8 + i];
        const bf16_t fh = (bf16_t)f;
        Ah[i] = fh; Al[i] = (bf16_t)(f - (float)fh);
      }
      #pragma unroll
      for (int n = 0; n < 2; ++n) {
        uA[n] = mfma16(Ah, wu1h[n][kk], uA[n]);
        uB[n] = mfma16(Ah, wu1l[n][kk], uB[n]);
        uC[n] = mfma16(Al, wu1h[n][kk], uC[n]);
      }
    }
    #pragma unroll
    for (int n = 0; n < 2; ++n) u1v[n] = uA[n] + uB[n] + uC[n];
    if (lane < 16) {
      s_u1[cc[0]] = fmaxf(u1v[0][0], 0.f);
      s_u1[cc[1]] = fmaxf(u1v[1][0], 0.f);
    }
    if constexpr (SENT) bar_lds(); else __syncthreads();

    // ---- update layer 2 -> publish ----
    f32x4 u2v[2];
    {
      f32x4 aA[2], aB[2], aC[2];
      #pragma unroll
      for (int n = 0; n < 2; ++n) {
        aA[n][0]=bs_u2[n]; aA[n][1]=bs_u2[n]; aA[n][2]=bs_u2[n]; aA[n][3]=bs_u2[n];
        aB[n][0]=0.f; aB[n][1]=0.f; aB[n][2]=0.f; aB[n][3]=0.f;
        aC[n] = aB[n];
      }
      #pragma unroll
      for (int kk = 0; kk < 4; ++kk) {
        bf16x8 Ah, Al;
        #pragma unroll
        for (int i = 0; i < 8; ++i) {
          const float f = s_u1[kk * 32 + g * 8 + i];
          const bf16_t fh = (bf16_t)f;
          Ah[i] = fh; Al[i] = (bf16_t)(f - (float)fh);
        }
        #pragma unroll
        for (int n = 0; n < 2; ++n) {
          aA[n] = mfma16(Ah, wu2h[n][kk], aA[n]);
          aB[n] = mfma16(Ah, wu2l[n][kk], aB[n]);
          aC[n] = mfma16(Al, wu2h[n][kk], aC[n]);
        }
      }
      #pragma unroll
      for (int n = 0; n < 2; ++n) u2v[n] = aA[n] + aB[n] + aC[n];
    }
    if (lane < 16) {  // D row 0 (all rows identical)
      #pragma unroll
      for (int n = 0; n < 2; ++n) {
        const float rv = fabsf(fmaxf(u2v[n][0], 0.f));  // fabs: kill -0.0
        if constexpr (SENT) {
          h[(size_t)v * HID + cc[n]] = rv;              // fp32 output (cached)
          const bf16_t rh = (bf16_t)rv;
          const bf16_t rl = (bf16_t)(rv - (float)rh);
          const unsigned pw = ((unsigned)bfbits(rh) << 16) | (unsigned)bfbits(rl);
          __hip_atomic_store(&h2u[(size_t)v * HID + cc[n]], pw,
                             __ATOMIC_RELAXED, __HIP_MEMORY_SCOPE_AGENT);
        } else {
          __hip_atomic_store(&h[(size_t)v * HID + cc[n]], rv,
                             __ATOMIC_RELAXED, __HIP_MEMORY_SCOPE_AGENT);
        }
      }
    }
    if constexpr (!SENT) {
      if (lane == 0)
        __hip_atomic_fetch_or(&flags[v * fs], 1 << wid, __ATOMIC_RELEASE,
                              __HIP_MEMORY_SCOPE_AGENT);
    }
    s_cur = s_nxt;
    // alignment barrier (required: prevents skew-1 s_m1 write/read overlap);
    // deliberately NO vmcnt drain -- publish stores overlap the next spin
    if constexpr (SENT) bar_align(); else __syncthreads();
  }
}

extern "C" void kernel_launch(void* const* d_in, const int* in_sizes, int n_in,
                              void* d_out, int out_size, void* d_ws, size_t ws_size,
                              hipStream_t stream) {
  const float* x    = (const float*)d_in[0];
  const int*   ei   = (const int*)  d_in[1];   // [2, E] int32; row 0 = src
  const float* attr = (const float*)d_in[2];
  const float* Wp   = (const float*)d_in[3];
  const float* bp   = (const float*)d_in[4];
  const float* Wm1  = (const float*)d_in[5];
  const float* bm1  = (const float*)d_in[6];
  const float* Wm2  = (const float*)d_in[7];
  const float* bm2  = (const float*)d_in[8];
  const float* Wu1  = (const float*)d_in[9];
  const float* bu1  = (const float*)d_in[10];
  const float* Wu2  = (const float*)d_in[11];
  const float* bu2  = (const float*)d_in[12];
  float* h = (float*)d_out;   // h state lives directly in d_out

  const size_t h2_bytes = (size_t)NN * HID * sizeof(unsigned);  // 4 MB
  const bool sent = ws_size >= h2_bytes;
  unsigned* h2u = (unsigned*)d_ws;
  int* flags    = (int*)d_ws;
  const int fs = sent ? 0 : ((ws_size >= (size_t)NN * 64 + 64) ? 16 : 1);

  k_h0<<<NN / 8, 128, 0, stream>>>(x, Wp, bp, h, h2u, flags, fs, sent ? 1 : 0);
  if (sent)
    k_dag<true><<<NBLK, 256, 0, stream>>>(ei, attr, Wm1, bm1, Wm2, bm2,
                                          Wu1, bu1, Wu2, bu2, h, h2u, flags, fs);
  else
    k_dag<false><<<NBLK, 256, 0, stream>>>(ei, attr, Wm1, bm1, Wm2, bm2,
                                           Wu1, bu1, Wu2, bu2, h, h2u, flags, fs);
}

// Round 5
// 643.560 us; speedup vs baseline: 5.1609x; 1.1251x over previous
//
#include <hip/hip_runtime.h>

#define NN   8192
#define DEG  16
#define HID  128
#define IND  128
#define ED   8
#define NBLK 256

typedef __bf16 bf16_t;
typedef __bf16 bf16x8 __attribute__((ext_vector_type(8)));
typedef float  f32x4  __attribute__((ext_vector_type(4)));
typedef unsigned long long u64;

static __device__ __forceinline__ f32x4 mfma16(bf16x8 a, bf16x8 b, f32x4 c) {
  return __builtin_amdgcn_mfma_f32_16x16x32_bf16(a, b, c, 0, 0, 0);
}
static __device__ __forceinline__ unsigned short bfbits(bf16_t x) {
  return __builtin_bit_cast(unsigned short, x);
}
static __device__ __forceinline__ bf16_t bits2bf(unsigned short x) {
  return __builtin_bit_cast(bf16_t, x);
}
// LDS-phase barrier: drain LDS ops only -- global loads/stores stay in flight.
static __device__ __forceinline__ void bar_lds() {
  __builtin_amdgcn_sched_barrier(0);
  asm volatile("s_waitcnt lgkmcnt(0)" ::: "memory");
  __builtin_amdgcn_s_barrier();
  __builtin_amdgcn_sched_barrier(0);
}

// ---------------- kernel 1: h0 = x @ Wp + bp ; init sync state ----------------
__global__ __launch_bounds__(128) void k_h0(const float* __restrict__ x,
                                            const float* __restrict__ Wp,
                                            const float* __restrict__ bp,
                                            float* __restrict__ h,
                                            unsigned* __restrict__ h2u,
                                            int* __restrict__ flags, int fs,
                                            int sent) {
  __shared__ float sx[8][IND];
  const int t  = threadIdx.x;      // 0..127 = output channel
  const int vb = blockIdx.x * 8;   // 8 nodes per block
  #pragma unroll
  for (int rr = 0; rr < 8; ++rr) sx[rr][t] = x[(size_t)(vb + rr) * IND + t];
  __syncthreads();
  float acc[8];
  const float bias = bp[t];
  #pragma unroll
  for (int rr = 0; rr < 8; ++rr) acc[rr] = bias;
  for (int k = 0; k < IND; ++k) {
    const float w = Wp[k * HID + t];
    #pragma unroll
    for (int rr = 0; rr < 8; ++rr) acc[rr] += sx[rr][k] * w;
  }
  #pragma unroll
  for (int rr = 0; rr < 8; ++rr) h[(size_t)(vb + rr) * HID + t] = acc[rr];
  if (sent) {
    // h2: row 0 = packed hi/lo of h0 (node 0 final); rows >=1 = sentinel
    #pragma unroll
    for (int rr = 0; rr < 8; ++rr) {
      unsigned val = 0xFFFFFFFFu;
      if (vb + rr == 0) {
        const float f = acc[rr];
        const bf16_t fh = (bf16_t)f;
        const bf16_t fl = (bf16_t)(f - (float)fh);
        val = ((unsigned)bfbits(fh) << 16) | (unsigned)bfbits(fl);
      }
      h2u[(size_t)(vb + rr) * HID + t] = val;
    }
  } else if (t < 8) {
    flags[(vb + t) * fs] = (vb + t == 0) ? 0xF : 0;
  }
}

// ---------------- kernel 2: persistent DAG executor ----------------
// 256 blocks (1/CU, co-resident), 4 waves, each wave owns two 16-ch output
// tiles; weights register-resident (bf16 hi/lo split). Consumers spin on the
// packed h2 row (bit31 sentinel): detect == gather. Only 3 barriers per node
// (end-of-loop alignment barrier proven redundant: identical unconditional
// barrier sequence per wave => arrivals pair; B1/B2/B3 fence all LDS hazards).
#define LOAD_WFRAGS(W, KROWS, NKK, ARRH, ARRL)                                \
  _Pragma("unroll")                                                           \
  for (int n = 0; n < 2; ++n) {                                               \
    _Pragma("unroll")                                                         \
    for (int kk = 0; kk < NKK; ++kk) {                                        \
      _Pragma("unroll")                                                       \
      for (int i = 0; i < 8; ++i) {                                           \
        const int k = kk * 32 + g * 8 + i;                                    \
        const float w = (k < KROWS) ? W[k * HID + cc[n]] : 0.f;               \
        const bf16_t wh = (bf16_t)w;                                          \
        ARRH[n][kk][i] = wh;                                                  \
        ARRL[n][kk][i] = (bf16_t)(w - (float)wh);                             \
      }                                                                       \
    }                                                                         \
  }

#define LOADQ()                                                               \
  _Pragma("unroll")                                                           \
  for (int kk = 0; kk < 4; ++kk) {                                            \
    _Pragma("unroll")                                                         \
    for (int u = 0; u < 4; ++u)                                               \
      q[kk * 4 + u] = __hip_atomic_load(hp + kk * 16 + u, __ATOMIC_RELAXED,   \
                                        __HIP_MEMORY_SCOPE_AGENT);            \
  }

template <bool SENT>
__global__ __launch_bounds__(256, 1) void k_dag(
    const int* __restrict__ ei, const float* __restrict__ attr,
    const float* __restrict__ Wm1, const float* __restrict__ bm1,
    const float* __restrict__ Wm2, const float* __restrict__ bm2,
    const float* __restrict__ Wu1, const float* __restrict__ bu1,
    const float* __restrict__ Wu2, const float* __restrict__ bu2,
    float* __restrict__ h, unsigned* __restrict__ h2u,
    int* __restrict__ flags, int fs) {
  const int tid  = threadIdx.x;
  const int lane = tid & 63;
  const int g    = lane >> 4;   // 16-lane group: k-block of A/B operands
  const int r    = lane & 15;   // A-row / B-col within tile
  const int wid  = tid >> 6;    // wave 0..3

  __shared__ bf16_t s_m1[16 * HID];            // msg1 acts, chunk-XOR swizzled
  __shared__ alignas(16) bf16_t s_agg[HID];    // bf16: read directly as frags
  __shared__ alignas(16) bf16_t s_u1[HID];

  int cc[2];
  cc[0] = (wid * 2 + 0) * 16 + r;
  cc[1] = (wid * 2 + 1) * 16 + r;

  // ---- register-resident weight fragments (bf16 hi/lo split) ----
  bf16x8 wm1h[2][5], wm1l[2][5], wm2h[2][4], wm2l[2][4];
  bf16x8 wu1h[2][8], wu1l[2][8], wu2h[2][4], wu2l[2][4];
  LOAD_WFRAGS(Wm1, 136, 5, wm1h, wm1l)   // rows 0..127 = h, 128..135 = attr
  LOAD_WFRAGS(Wm2, 128, 4, wm2h, wm2l)
  LOAD_WFRAGS(Wu1, 256, 8, wu1h, wu1l)
  LOAD_WFRAGS(Wu2, 128, 4, wu2h, wu2l)
  float bs_m1[2], bs_m2[2], bs_u1[2], bs_u2[2];
  #pragma unroll
  for (int n = 0; n < 2; ++n) {
    bs_m1[n] = bm1[cc[n]]; bs_m2[n] = bm2[cc[n]];
    bs_u1[n] = bu1[cc[n]]; bs_u2[n] = bu2[cc[n]];
  }

  const int v0 = 1 + (int)blockIdx.x;
  int s_cur = (v0 < NN) ? ei[(v0 - 1) * DEG + r] : 0;

  for (int v = v0; v < NN; v += NBLK) {
    // ---- off-chain: next edge list, own h0 row -> fragments, attr frag ----
    const int vn = (v + NBLK < NN) ? v + NBLK : v;
    const int s_nxt = ei[(vn - 1) * DEG + r];

    bf16x8 hvh[4], hvl[4];
    {
      const float* hvp = h + (size_t)v * HID + g * 8;
      #pragma unroll
      for (int kk = 0; kk < 4; ++kk) {
        const f32x4 p0 = *(const f32x4*)(hvp + kk * 32);
        const f32x4 p1 = *(const f32x4*)(hvp + kk * 32 + 4);
        #pragma unroll
        for (int i = 0; i < 4; ++i) {
          const float f0 = p0[i], f1 = p1[i];
          const bf16_t f0h = (bf16_t)f0, f1h = (bf16_t)f1;
          hvh[kk][i]     = f0h; hvl[kk][i]     = (bf16_t)(f0 - (float)f0h);
          hvh[kk][4 + i] = f1h; hvl[kk][4 + i] = (bf16_t)(f1 - (float)f1h);
        }
      }
    }
    bf16x8 a4h;
    #pragma unroll
    for (int i = 0; i < 8; ++i) a4h[i] = (bf16_t)0.f;
    if (g == 0) {
      const f32x4* ap = (const f32x4*)(attr + ((size_t)(v - 1) * DEG + r) * ED);
      const f32x4 a0 = ap[0], a1 = ap[1];
      #pragma unroll
      for (int i = 0; i < 4; ++i) {
        a4h[i] = (bf16_t)a0[i]; a4h[4 + i] = (bf16_t)a1[i];
      }
    }

    // ---- issue poll/gather loads ----
    u64 q[16];
    const u64* hp =
        (const u64*)((SENT ? (const void*)h2u : (const void*)h)) +
        (size_t)s_cur * (HID / 2) + g * 4;
    LOADQ();

    // ---- off-chain MFMA work overlapping the in-flight poll loads ----
    // (a) u1 h0_v-half (own data + weights only); keep activation-lo here
    f32x4 uA[2], uB[2], uC[2];
    #pragma unroll
    for (int n = 0; n < 2; ++n) {
      uA[n][0]=bs_u1[n]; uA[n][1]=bs_u1[n]; uA[n][2]=bs_u1[n]; uA[n][3]=bs_u1[n];
      uB[n][0]=0.f; uB[n][1]=0.f; uB[n][2]=0.f; uB[n][3]=0.f;
      uC[n] = uB[n];
    }
    #pragma unroll
    for (int kk = 0; kk < 4; ++kk) {
      #pragma unroll
      for (int n = 0; n < 2; ++n) {
        uA[n] = mfma16(hvh[kk], wu1h[n][kk], uA[n]);
        uB[n] = mfma16(hvh[kk], wu1l[n][kk], uB[n]);
        uC[n] = mfma16(hvl[kk], wu1h[n][kk], uC[n]);
      }
    }
    // (b) m1 init + attr k-step (independent of preds)
    f32x4 mA[2], mB[2], mC[2];
    #pragma unroll
    for (int n = 0; n < 2; ++n) {
      mA[n][0]=bs_m1[n]; mA[n][1]=bs_m1[n]; mA[n][2]=bs_m1[n]; mA[n][3]=bs_m1[n];
      mB[n][0]=0.f; mB[n][1]=0.f; mB[n][2]=0.f; mB[n][3]=0.f;
      mC[n] = mB[n];
    }
    #pragma unroll
    for (int n = 0; n < 2; ++n) {
      mA[n] = mfma16(a4h, wm1h[n][4], mA[n]);
      mB[n] = mfma16(a4h, wm1l[n][4], mB[n]);
    }

    // ---- spin: data IS the sync (bit31 of each packed u32 = sentinel) ----
    if constexpr (SENT) {
      bool ok = false;
      int guard = 0;
      for (;;) {
        if (!ok) {
          u64 m = 0;
          #pragma unroll
          for (int i = 0; i < 16; ++i) m |= q[i];
          ok = (s_cur == 0) || ((m & 0x8000000080000000ull) == 0);
        }
        if (__all(ok)) break;
        if (++guard > (1 << 13)) break;  // fail-safe: wrong answer, never hang
        if (!ok) LOADQ();
      }
    } else {
      const int* fp = flags + s_cur * fs;
      int fw = __hip_atomic_load(fp, __ATOMIC_RELAXED, __HIP_MEMORY_SCOPE_AGENT);
      int guard = 0;
      while (fw != 0xF && ++guard < (1 << 15)) {
        __builtin_amdgcn_s_sleep(1);
        fw = __hip_atomic_load(fp, __ATOMIC_RELAXED, __HIP_MEMORY_SCOPE_AGENT);
      }
      asm volatile("" ::: "memory");  // gathers stay below the spin
      LOADQ();
    }

    // ---- A fragments: SENT = pure bit-split; fallback = f32 convert ----
    bf16x8 ah[4], al[4];
    #pragma unroll
    for (int kk = 0; kk < 4; ++kk) {
      #pragma unroll
      for (int u = 0; u < 4; ++u) {
        #pragma unroll
        for (int b = 0; b < 2; ++b) {
          const unsigned w = (unsigned)(q[kk * 4 + u] >> (32 * b));
          if constexpr (SENT) {
            ah[kk][u * 2 + b] = bits2bf((unsigned short)(w >> 16));
            al[kk][u * 2 + b] = bits2bf((unsigned short)(w & 0xFFFFu));
          } else {
            const float f = __uint_as_float(w);
            const bf16_t fh = (bf16_t)f;
            ah[kk][u * 2 + b] = fh;
            al[kk][u * 2 + b] = (bf16_t)(f - (float)fh);
          }
        }
      }
    }

    // ---- msg layer 1: 4 pred k-steps (3 parallel chains; lo kept: recurrent) ----
    f32x4 m1[2];
    #pragma unroll
    for (int kk = 0; kk < 4; ++kk) {
      #pragma unroll
      for (int n = 0; n < 2; ++n) {
        mA[n] = mfma16(ah[kk], wm1h[n][kk], mA[n]);
        mB[n] = mfma16(ah[kk], wm1l[n][kk], mB[n]);
        mC[n] = mfma16(al[kk], wm1h[n][kk], mC[n]);
      }
    }
    #pragma unroll
    for (int n = 0; n < 2; ++n) m1[n] = mA[n] + mB[n] + mC[n];
    // relu -> bf16 -> LDS with chunk-XOR swizzle (conflict-free b128 reads)
    #pragma unroll
    for (int n = 0; n < 2; ++n) {
      const int c = cc[n], ch16 = c >> 3;
      #pragma unroll
      for (int reg = 0; reg < 4; ++reg) {
        const int j = g * 4 + reg;  // edge row (D layout: row = 4*(lane>>4)+reg)
        s_m1[j * HID + ((ch16 ^ j) * 8) + (c & 7)] = (bf16_t)fmaxf(m1[n][reg], 0.f);
      }
    }
    if constexpr (SENT) bar_lds(); else __syncthreads();   // B1

    // ---- msg layer 2 + mean aggregation (cnt == 16 for all v>=1) ----
    f32x4 m2[2];
    {
      f32x4 aA[2], aB[2];
      #pragma unroll
      for (int n = 0; n < 2; ++n) {
        aA[n][0]=bs_m2[n]; aA[n][1]=bs_m2[n]; aA[n][2]=bs_m2[n]; aA[n][3]=bs_m2[n];
        aB[n][0]=0.f; aB[n][1]=0.f; aB[n][2]=0.f; aB[n][3]=0.f;
      }
      #pragma unroll
      for (int kk = 0; kk < 4; ++kk) {
        const int phys = (kk * 4 + g) ^ r;
        const bf16x8 a = *(const bf16x8*)(s_m1 + r * HID + phys * 8);
        #pragma unroll
        for (int n = 0; n < 2; ++n) {
          aA[n] = mfma16(a, wm2h[n][kk], aA[n]);
          aB[n] = mfma16(a, wm2l[n][kk], aB[n]);
        }
      }
      #pragma unroll
      for (int n = 0; n < 2; ++n) m2[n] = aA[n] + aB[n];
    }
    #pragma unroll
    for (int n = 0; n < 2; ++n) {
      float s = fmaxf(m2[n][0],0.f)+fmaxf(m2[n][1],0.f)+fmaxf(m2[n][2],0.f)+fmaxf(m2[n][3],0.f);
      s += __shfl_xor(s, 16, 64);
      s += __shfl_xor(s, 32, 64);
      if (lane < 16) s_agg[cc[n]] = (bf16_t)(s * 0.0625f);  // bf16 once
    }
    if constexpr (SENT) bar_lds(); else __syncthreads();   // B2

    // ---- update layer 1, agg-half (hi + weight-lo chains; act-lo dropped) ----
    f32x4 u1v[2];
    #pragma unroll
    for (int kk = 4; kk < 8; ++kk) {
      const bf16x8 Ah = *(const bf16x8*)(s_agg + (kk - 4) * 32 + g * 8);
      #pragma unroll
      for (int n = 0; n < 2; ++n) {
        uA[n] = mfma16(Ah, wu1h[n][kk], uA[n]);
        uB[n] = mfma16(Ah, wu1l[n][kk], uB[n]);
      }
    }
    #pragma unroll
    for (int n = 0; n < 2; ++n) u1v[n] = uA[n] + uB[n] + uC[n];
    if (lane < 16) {
      s_u1[cc[0]] = (bf16_t)fmaxf(u1v[0][0], 0.f);
      s_u1[cc[1]] = (bf16_t)fmaxf(u1v[1][0], 0.f);
    }
    if constexpr (SENT) bar_lds(); else __syncthreads();   // B3

    // ---- update layer 2 -> publish (hi + weight-lo chains) ----
    f32x4 u2v[2];
    {
      f32x4 aA[2], aB[2];
      #pragma unroll
      for (int n = 0; n < 2; ++n) {
        aA[n][0]=bs_u2[n]; aA[n][1]=bs_u2[n]; aA[n][2]=bs_u2[n]; aA[n][3]=bs_u2[n];
        aB[n][0]=0.f; aB[n][1]=0.f; aB[n][2]=0.f; aB[n][3]=0.f;
      }
      #pragma unroll
      for (int kk = 0; kk < 4; ++kk) {
        const bf16x8 Ah = *(const bf16x8*)(s_u1 + kk * 32 + g * 8);
        #pragma unroll
        for (int n = 0; n < 2; ++n) {
          aA[n] = mfma16(Ah, wu2h[n][kk], aA[n]);
          aB[n] = mfma16(Ah, wu2l[n][kk], aB[n]);
        }
      }
      #pragma unroll
      for (int n = 0; n < 2; ++n) u2v[n] = aA[n] + aB[n];
    }
    if (lane < 16) {  // D row 0 (all rows identical)
      #pragma unroll
      for (int n = 0; n < 2; ++n) {
        const float rv = fabsf(fmaxf(u2v[n][0], 0.f));  // fabs: kill -0.0
        if constexpr (SENT) {
          h[(size_t)v * HID + cc[n]] = rv;              // fp32 output (cached)
          const bf16_t rh = (bf16_t)rv;
          const bf16_t rl = (bf16_t)(rv - (float)rh);
          const unsigned pw = ((unsigned)bfbits(rh) << 16) | (unsigned)bfbits(rl);
          __hip_atomic_store(&h2u[(size_t)v * HID + cc[n]], pw,
                             __ATOMIC_RELAXED, __HIP_MEMORY_SCOPE_AGENT);
        } else {
          __hip_atomic_store(&h[(size_t)v * HID + cc[n]], rv,
                             __ATOMIC_RELAXED, __HIP_MEMORY_SCOPE_AGENT);
        }
      }
    }
    if constexpr (!SENT) {
      if (lane == 0)
        __hip_atomic_fetch_or(&flags[v * fs], 1 << wid, __ATOMIC_RELEASE,
                              __HIP_MEMORY_SCOPE_AGENT);
    }
    s_cur = s_nxt;
    // SENT: no end-of-loop barrier (B1/B2/B3 fence all cross-iter hazards;
    // barrier arrivals pair because the sequence is unconditional & uniform)
    if constexpr (!SENT) __syncthreads();
  }
}

extern "C" void kernel_launch(void* const* d_in, const int* in_sizes, int n_in,
                              void* d_out, int out_size, void* d_ws, size_t ws_size,
                              hipStream_t stream) {
  const float* x    = (const float*)d_in[0];
  const int*   ei   = (const int*)  d_in[1];   // [2, E] int32; row 0 = src
  const float* attr = (const float*)d_in[2];
  const float* Wp   = (const float*)d_in[3];
  const float* bp   = (const float*)d_in[4];
  const float* Wm1  = (const float*)d_in[5];
  const float* bm1  = (const float*)d_in[6];
  const float* Wm2  = (const float*)d_in[7];
  const float* bm2  = (const float*)d_in[8];
  const float* Wu1  = (const float*)d_in[9];
  const float* bu1  = (const float*)d_in[10];
  const float* Wu2  = (const float*)d_in[11];
  const float* bu2  = (const float*)d_in[12];
  float* h = (float*)d_out;   // h state lives directly in d_out

  const size_t h2_bytes = (size_t)NN * HID * sizeof(unsigned);  // 4 MB
  const bool sent = ws_size >= h2_bytes;
  unsigned* h2u = (unsigned*)d_ws;
  int* flags    = (int*)d_ws;
  const int fs = sent ? 0 : ((ws_size >= (size_t)NN * 64 + 64) ? 16 : 1);

  k_h0<<<NN / 8, 128, 0, stream>>>(x, Wp, bp, h, h2u, flags, fs, sent ? 1 : 0);
  if (sent)
    k_dag<true><<<NBLK, 256, 0, stream>>>(ei, attr, Wm1, bm1, Wm2, bm2,
                                          Wu1, bu1, Wu2, bu2, h, h2u, flags, fs);
  else
    k_dag<false><<<NBLK, 256, 0, stream>>>(ei, attr, Wm1, bm1, Wm2, bm2,
                                           Wu1, bu1, Wu2, bu2, h, h2u, flags, fs);
}

// Round 6
// 636.500 us; speedup vs baseline: 5.2182x; 1.0111x over previous
//
#include <hip/hip_runtime.h>

#define NN   8192
#define DEG  16
#define HID  128
#define IND  128
#define ED   8
#define NBLK 256

typedef __bf16 bf16_t;
typedef __bf16 bf16x8 __attribute__((ext_vector_type(8)));
typedef float  f32x4  __attribute__((ext_vector_type(4)));
typedef unsigned long long u64;

static __device__ __forceinline__ f32x4 mfma16(bf16x8 a, bf16x8 b, f32x4 c) {
  return __builtin_amdgcn_mfma_f32_16x16x32_bf16(a, b, c, 0, 0, 0);
}
static __device__ __forceinline__ unsigned short bfbits(bf16_t x) {
  return __builtin_bit_cast(unsigned short, x);
}
static __device__ __forceinline__ bf16_t bits2bf(unsigned short x) {
  return __builtin_bit_cast(bf16_t, x);
}
// LDS-phase barrier: drain LDS ops only -- global loads/stores stay in flight.
static __device__ __forceinline__ void bar_lds() {
  __builtin_amdgcn_sched_barrier(0);
  asm volatile("s_waitcnt lgkmcnt(0)" ::: "memory");
  __builtin_amdgcn_s_barrier();
  __builtin_amdgcn_sched_barrier(0);
}
// full-drain barrier (used once, before the output tail)
static __device__ __forceinline__ void bar_full() {
  __builtin_amdgcn_sched_barrier(0);
  asm volatile("s_waitcnt vmcnt(0) lgkmcnt(0)" ::: "memory");
  __builtin_amdgcn_s_barrier();
  __builtin_amdgcn_sched_barrier(0);
}

// ---------------- kernel 1: h0 = x @ Wp + bp ; init sync state ----------------
__global__ __launch_bounds__(128) void k_h0(const float* __restrict__ x,
                                            const float* __restrict__ Wp,
                                            const float* __restrict__ bp,
                                            float* __restrict__ h,
                                            unsigned* __restrict__ h2u,
                                            int* __restrict__ flags, int fs,
                                            int sent) {
  __shared__ float sx[8][IND];
  const int t  = threadIdx.x;      // 0..127 = output channel
  const int vb = blockIdx.x * 8;   // 8 nodes per block
  #pragma unroll
  for (int rr = 0; rr < 8; ++rr) sx[rr][t] = x[(size_t)(vb + rr) * IND + t];
  __syncthreads();
  float acc[8];
  const float bias = bp[t];
  #pragma unroll
  for (int rr = 0; rr < 8; ++rr) acc[rr] = bias;
  for (int k = 0; k < IND; ++k) {
    const float w = Wp[k * HID + t];
    #pragma unroll
    for (int rr = 0; rr < 8; ++rr) acc[rr] += sx[rr][k] * w;
  }
  #pragma unroll
  for (int rr = 0; rr < 8; ++rr) h[(size_t)(vb + rr) * HID + t] = acc[rr];
  if (sent) {
    // h2: row 0 = packed hi/lo of h0 (node 0 final); rows >=1 = sentinel
    #pragma unroll
    for (int rr = 0; rr < 8; ++rr) {
      unsigned val = 0xFFFFFFFFu;
      if (vb + rr == 0) {
        const float f = acc[rr];
        const bf16_t fh = (bf16_t)f;
        const bf16_t fl = (bf16_t)(f - (float)fh);
        val = ((unsigned)bfbits(fh) << 16) | (unsigned)bfbits(fl);
      }
      h2u[(size_t)(vb + rr) * HID + t] = val;
    }
  } else if (t < 8) {
    flags[(vb + t) * fs] = (vb + t == 0) ? 0xF : 0;
  }
}

// ---------------- kernel 2: persistent DAG executor ----------------
// 256 blocks (1/CU, co-resident), 4 waves, each wave owns two 16-ch output
// tiles; weights register-resident (bf16 hi/lo split). Consumers spin on the
// packed h2 row (bit31 sentinel): detect == gather. 3 barriers per node.
// fp32 h output written once in a post-loop tail (off the critical chain).
#define LOAD_WFRAGS(W, KROWS, NKK, ARRH, ARRL)                                \
  _Pragma("unroll")                                                           \
  for (int n = 0; n < 2; ++n) {                                               \
    _Pragma("unroll")                                                         \
    for (int kk = 0; kk < NKK; ++kk) {                                        \
      _Pragma("unroll")                                                       \
      for (int i = 0; i < 8; ++i) {                                           \
        const int k = kk * 32 + g * 8 + i;                                    \
        const float w = (k < KROWS) ? W[k * HID + cc[n]] : 0.f;               \
        const bf16_t wh = (bf16_t)w;                                          \
        ARRH[n][kk][i] = wh;                                                  \
        ARRL[n][kk][i] = (bf16_t)(w - (float)wh);                             \
      }                                                                       \
    }                                                                         \
  }

#define LOADQ()                                                               \
  _Pragma("unroll")                                                           \
  for (int kk = 0; kk < 4; ++kk) {                                            \
    _Pragma("unroll")                                                         \
    for (int u = 0; u < 4; ++u)                                               \
      q[kk * 4 + u] = __hip_atomic_load(hp + kk * 16 + u, __ATOMIC_RELAXED,   \
                                        __HIP_MEMORY_SCOPE_AGENT);            \
  }

#define ZERO4(a) { a[0][0]=0.f;a[0][1]=0.f;a[0][2]=0.f;a[0][3]=0.f; a[1]=a[0]; }
#define BIAS4(a, b) { a[0][0]=b[0];a[0][1]=b[0];a[0][2]=b[0];a[0][3]=b[0];    \
                      a[1][0]=b[1];a[1][1]=b[1];a[1][2]=b[1];a[1][3]=b[1]; }

template <bool SENT>
__global__ __launch_bounds__(256, 1) void k_dag(
    const int* __restrict__ ei, const float* __restrict__ attr,
    const float* __restrict__ Wm1, const float* __restrict__ bm1,
    const float* __restrict__ Wm2, const float* __restrict__ bm2,
    const float* __restrict__ Wu1, const float* __restrict__ bu1,
    const float* __restrict__ Wu2, const float* __restrict__ bu2,
    float* __restrict__ h, unsigned* __restrict__ h2u,
    int* __restrict__ flags, int fs) {
  const int tid  = threadIdx.x;
  const int lane = tid & 63;
  const int g    = lane >> 4;   // 16-lane group: k-block of A/B operands
  const int r    = lane & 15;   // A-row / B-col within tile
  const int wid  = tid >> 6;    // wave 0..3

  __shared__ bf16_t s_m1[16 * HID];            // msg1 acts, chunk-XOR swizzled
  __shared__ alignas(16) bf16_t s_agg[HID];    // bf16: read directly as frags
  __shared__ alignas(16) bf16_t s_u1[HID];

  int cc[2];
  cc[0] = (wid * 2 + 0) * 16 + r;
  cc[1] = (wid * 2 + 1) * 16 + r;

  // ---- register-resident weight fragments (bf16 hi/lo split) ----
  bf16x8 wm1h[2][5], wm1l[2][5], wm2h[2][4], wm2l[2][4];
  bf16x8 wu1h[2][8], wu1l[2][8], wu2h[2][4], wu2l[2][4];
  LOAD_WFRAGS(Wm1, 136, 5, wm1h, wm1l)   // rows 0..127 = h, 128..135 = attr
  LOAD_WFRAGS(Wm2, 128, 4, wm2h, wm2l)
  LOAD_WFRAGS(Wu1, 256, 8, wu1h, wu1l)
  LOAD_WFRAGS(Wu2, 128, 4, wu2h, wu2l)
  float bs_m1[2], bs_m2[2], bs_u1[2], bs_u2[2];
  #pragma unroll
  for (int n = 0; n < 2; ++n) {
    bs_m1[n] = bm1[cc[n]]; bs_m2[n] = bm2[cc[n]];
    bs_u1[n] = bu1[cc[n]]; bs_u2[n] = bu2[cc[n]];
  }

  const int v0 = 1 + (int)blockIdx.x;
  int s_cur = (v0 < NN) ? ei[(v0 - 1) * DEG + r] : 0;

  for (int v = v0; v < NN; v += NBLK) {
    // ---- poll/gather loads issue FIRST (minimize detect phase delay) ----
    u64 q[16];
    const u64* hp =
        (const u64*)((SENT ? (const void*)h2u : (const void*)h)) +
        (size_t)s_cur * (HID / 2) + g * 4;
    LOADQ();

    // ---- off-chain: next edge list, own h0 row -> fragments, attr frag ----
    const int vn = (v + NBLK < NN) ? v + NBLK : v;
    const int s_nxt = ei[(vn - 1) * DEG + r];

    bf16x8 hvh[4], hvl[4];
    {
      const float* hvp = h + (size_t)v * HID + g * 8;
      #pragma unroll
      for (int kk = 0; kk < 4; ++kk) {
        const f32x4 p0 = *(const f32x4*)(hvp + kk * 32);
        const f32x4 p1 = *(const f32x4*)(hvp + kk * 32 + 4);
        #pragma unroll
        for (int i = 0; i < 4; ++i) {
          const float f0 = p0[i], f1 = p1[i];
          const bf16_t f0h = (bf16_t)f0, f1h = (bf16_t)f1;
          hvh[kk][i]     = f0h; hvl[kk][i]     = (bf16_t)(f0 - (float)f0h);
          hvh[kk][4 + i] = f1h; hvl[kk][4 + i] = (bf16_t)(f1 - (float)f1h);
        }
      }
    }
    bf16x8 a4h;
    #pragma unroll
    for (int i = 0; i < 8; ++i) a4h[i] = (bf16_t)0.f;
    if (g == 0) {
      const f32x4* ap = (const f32x4*)(attr + ((size_t)(v - 1) * DEG + r) * ED);
      const f32x4 a0 = ap[0], a1 = ap[1];
      #pragma unroll
      for (int i = 0; i < 4; ++i) {
        a4h[i] = (bf16_t)a0[i]; a4h[4 + i] = (bf16_t)a1[i];
      }
    }

    // ---- off-chain MFMA work overlapping the in-flight poll loads ----
    // (a) u1 h0_v-half (own data + weights only)
    f32x4 uA[2], uB[2], uC[2], uD[2], uE[2];
    BIAS4(uA, bs_u1) ZERO4(uB) ZERO4(uC) ZERO4(uD) ZERO4(uE)
    #pragma unroll
    for (int kk = 0; kk < 4; ++kk) {
      #pragma unroll
      for (int n = 0; n < 2; ++n) {
        uA[n] = mfma16(hvh[kk], wu1h[n][kk], uA[n]);
        uB[n] = mfma16(hvh[kk], wu1l[n][kk], uB[n]);
        uC[n] = mfma16(hvl[kk], wu1h[n][kk], uC[n]);
      }
    }
    // (b) m1 init + attr k-step (independent of preds); 6 accumulators so the
    // post-detect pred k-steps run depth-2 instead of depth-4
    f32x4 mA[2], mB[2], mC[2], mD[2], mE[2], mF[2];
    BIAS4(mA, bs_m1) ZERO4(mB) ZERO4(mC) ZERO4(mD) ZERO4(mE) ZERO4(mF)
    #pragma unroll
    for (int n = 0; n < 2; ++n) {
      mA[n] = mfma16(a4h, wm1h[n][4], mA[n]);
      mB[n] = mfma16(a4h, wm1l[n][4], mB[n]);
    }

    // ---- spin: data IS the sync (bit31 of each packed u32 = sentinel) ----
    if constexpr (SENT) {
      bool ok = false;
      int guard = 0;
      for (;;) {
        if (!ok) {
          u64 m = 0;
          #pragma unroll
          for (int i = 0; i < 16; ++i) m |= q[i];
          ok = (s_cur == 0) || ((m & 0x8000000080000000ull) == 0);
        }
        if (__all(ok)) break;
        if (++guard > (1 << 13)) break;  // fail-safe: wrong answer, never hang
        if (!ok) LOADQ();
      }
    } else {
      const int* fp = flags + s_cur * fs;
      int fw = __hip_atomic_load(fp, __ATOMIC_RELAXED, __HIP_MEMORY_SCOPE_AGENT);
      int guard = 0;
      while (fw != 0xF && ++guard < (1 << 15)) {
        __builtin_amdgcn_s_sleep(1);
        fw = __hip_atomic_load(fp, __ATOMIC_RELAXED, __HIP_MEMORY_SCOPE_AGENT);
      }
      asm volatile("" ::: "memory");  // gathers stay below the spin
      LOADQ();
    }

    // ---- A fragments: SENT = pure bit-split; fallback = f32 convert ----
    bf16x8 ah[4], al[4];
    #pragma unroll
    for (int kk = 0; kk < 4; ++kk) {
      #pragma unroll
      for (int u = 0; u < 4; ++u) {
        #pragma unroll
        for (int b = 0; b < 2; ++b) {
          const unsigned w = (unsigned)(q[kk * 4 + u] >> (32 * b));
          if constexpr (SENT) {
            ah[kk][u * 2 + b] = bits2bf((unsigned short)(w >> 16));
            al[kk][u * 2 + b] = bits2bf((unsigned short)(w & 0xFFFFu));
          } else {
            const float f = __uint_as_float(w);
            const bf16_t fh = (bf16_t)f;
            ah[kk][u * 2 + b] = fh;
            al[kk][u * 2 + b] = (bf16_t)(f - (float)fh);
          }
        }
      }
    }

    // ---- msg layer 1: 4 pred k-steps, depth-2 chains (kk01 -> ABC, kk23 -> DEF) ----
    f32x4 m1[2];
    #pragma unroll
    for (int kk = 0; kk < 2; ++kk) {
      #pragma unroll
      for (int n = 0; n < 2; ++n) {
        mA[n] = mfma16(ah[kk], wm1h[n][kk], mA[n]);
        mB[n] = mfma16(ah[kk], wm1l[n][kk], mB[n]);
        mC[n] = mfma16(al[kk], wm1h[n][kk], mC[n]);
        mD[n] = mfma16(ah[kk + 2], wm1h[n][kk + 2], mD[n]);
        mE[n] = mfma16(ah[kk + 2], wm1l[n][kk + 2], mE[n]);
        mF[n] = mfma16(al[kk + 2], wm1h[n][kk + 2], mF[n]);
      }
    }
    #pragma unroll
    for (int n = 0; n < 2; ++n)
      m1[n] = ((mA[n] + mB[n]) + (mC[n] + mD[n])) + (mE[n] + mF[n]);
    // relu -> bf16 -> LDS with chunk-XOR swizzle (conflict-free b128 reads)
    #pragma unroll
    for (int n = 0; n < 2; ++n) {
      const int c = cc[n], ch16 = c >> 3;
      #pragma unroll
      for (int reg = 0; reg < 4; ++reg) {
        const int j = g * 4 + reg;  // edge row (D layout: row = 4*(lane>>4)+reg)
        s_m1[j * HID + ((ch16 ^ j) * 8) + (c & 7)] = (bf16_t)fmaxf(m1[n][reg], 0.f);
      }
    }
    if constexpr (SENT) bar_lds(); else __syncthreads();   // B1

    // ---- msg layer 2 + mean aggregation (depth-2 chains) ----
    f32x4 m2[2];
    {
      f32x4 aA[2], aB[2], aC[2], aD[2];
      BIAS4(aA, bs_m2) ZERO4(aB) ZERO4(aC) ZERO4(aD)
      #pragma unroll
      for (int kk = 0; kk < 2; ++kk) {
        const int ph0 = (kk * 4 + g) ^ r;
        const int ph1 = ((kk + 2) * 4 + g) ^ r;
        const bf16x8 a0 = *(const bf16x8*)(s_m1 + r * HID + ph0 * 8);
        const bf16x8 a1 = *(const bf16x8*)(s_m1 + r * HID + ph1 * 8);
        #pragma unroll
        for (int n = 0; n < 2; ++n) {
          aA[n] = mfma16(a0, wm2h[n][kk], aA[n]);
          aB[n] = mfma16(a0, wm2l[n][kk], aB[n]);
          aC[n] = mfma16(a1, wm2h[n][kk + 2], aC[n]);
          aD[n] = mfma16(a1, wm2l[n][kk + 2], aD[n]);
        }
      }
      #pragma unroll
      for (int n = 0; n < 2; ++n) m2[n] = (aA[n] + aB[n]) + (aC[n] + aD[n]);
    }
    #pragma unroll
    for (int n = 0; n < 2; ++n) {
      float s = fmaxf(m2[n][0],0.f)+fmaxf(m2[n][1],0.f)+fmaxf(m2[n][2],0.f)+fmaxf(m2[n][3],0.f);
      s += __shfl_xor(s, 16, 64);
      s += __shfl_xor(s, 32, 64);
      if (lane < 16) s_agg[cc[n]] = (bf16_t)(s * 0.0625f);  // bf16 once
    }
    if constexpr (SENT) bar_lds(); else __syncthreads();   // B2

    // ---- update layer 1, agg-half (depth-2: kk45 -> uA/uB, kk67 -> uD/uE) ----
    f32x4 u1v[2];
    #pragma unroll
    for (int kk = 4; kk < 6; ++kk) {
      const bf16x8 Ah0 = *(const bf16x8*)(s_agg + (kk - 4) * 32 + g * 8);
      const bf16x8 Ah1 = *(const bf16x8*)(s_agg + (kk - 2) * 32 + g * 8);
      #pragma unroll
      for (int n = 0; n < 2; ++n) {
        uA[n] = mfma16(Ah0, wu1h[n][kk], uA[n]);
        uB[n] = mfma16(Ah0, wu1l[n][kk], uB[n]);
        uD[n] = mfma16(Ah1, wu1h[n][kk + 2], uD[n]);
        uE[n] = mfma16(Ah1, wu1l[n][kk + 2], uE[n]);
      }
    }
    #pragma unroll
    for (int n = 0; n < 2; ++n)
      u1v[n] = ((uA[n] + uB[n]) + (uC[n] + uD[n])) + uE[n];
    if (lane < 16) {
      s_u1[cc[0]] = (bf16_t)fmaxf(u1v[0][0], 0.f);
      s_u1[cc[1]] = (bf16_t)fmaxf(u1v[1][0], 0.f);
    }
    if constexpr (SENT) bar_lds(); else __syncthreads();   // B3

    // ---- update layer 2 -> publish (depth-2 chains) ----
    f32x4 u2v[2];
    {
      f32x4 aA[2], aB[2], aC[2], aD[2];
      BIAS4(aA, bs_u2) ZERO4(aB) ZERO4(aC) ZERO4(aD)
      #pragma unroll
      for (int kk = 0; kk < 2; ++kk) {
        const bf16x8 Ah0 = *(const bf16x8*)(s_u1 + kk * 32 + g * 8);
        const bf16x8 Ah1 = *(const bf16x8*)(s_u1 + (kk + 2) * 32 + g * 8);
        #pragma unroll
        for (int n = 0; n < 2; ++n) {
          aA[n] = mfma16(Ah0, wu2h[n][kk], aA[n]);
          aB[n] = mfma16(Ah0, wu2l[n][kk], aB[n]);
          aC[n] = mfma16(Ah1, wu2h[n][kk + 2], aC[n]);
          aD[n] = mfma16(Ah1, wu2l[n][kk + 2], aD[n]);
        }
      }
      #pragma unroll
      for (int n = 0; n < 2; ++n) u2v[n] = (aA[n] + aB[n]) + (aC[n] + aD[n]);
    }
    if (lane < 16) {  // D row 0 (all rows identical)
      #pragma unroll
      for (int n = 0; n < 2; ++n) {
        const float rv = fabsf(fmaxf(u2v[n][0], 0.f));  // fabs: kill -0.0
        if constexpr (SENT) {
          // sync channel only -- fp32 h written in the post-loop tail
          const bf16_t rh = (bf16_t)rv;
          const bf16_t rl = (bf16_t)(rv - (float)rh);
          const unsigned pw = ((unsigned)bfbits(rh) << 16) | (unsigned)bfbits(rl);
          __hip_atomic_store(&h2u[(size_t)v * HID + cc[n]], pw,
                             __ATOMIC_RELAXED, __HIP_MEMORY_SCOPE_AGENT);
        } else {
          __hip_atomic_store(&h[(size_t)v * HID + cc[n]], rv,
                             __ATOMIC_RELAXED, __HIP_MEMORY_SCOPE_AGENT);
        }
      }
    }
    if constexpr (!SENT) {
      if (lane == 0)
        __hip_atomic_fetch_or(&flags[v * fs], 1 << wid, __ATOMIC_RELEASE,
                              __HIP_MEMORY_SCOPE_AGENT);
    }
    s_cur = s_nxt;
    if constexpr (!SENT) __syncthreads();
  }

  // ---- output tail: reconstruct fp32 h rows from h2 (off critical chain) ----
  if constexpr (SENT) {
    bar_full();  // own h2 stores must be MALL-visible before re-read
    const int half = tid >> 7;          // 0/1: two nodes per iteration
    const int c    = tid & 127;
    #pragma unroll 4
    for (int v = v0 + half * NBLK; v < NN; v += 2 * NBLK) {
      const unsigned w = __hip_atomic_load(&h2u[(size_t)v * HID + c],
                                           __ATOMIC_RELAXED,
                                           __HIP_MEMORY_SCOPE_AGENT);
      h[(size_t)v * HID + c] =
          (float)bits2bf((unsigned short)(w >> 16)) +
          (float)bits2bf((unsigned short)(w & 0xFFFFu));
    }
  }
}

extern "C" void kernel_launch(void* const* d_in, const int* in_sizes, int n_in,
                              void* d_out, int out_size, void* d_ws, size_t ws_size,
                              hipStream_t stream) {
  const float* x    = (const float*)d_in[0];
  const int*   ei   = (const int*)  d_in[1];   // [2, E] int32; row 0 = src
  const float* attr = (const float*)d_in[2];
  const float* Wp   = (const float*)d_in[3];
  const float* bp   = (const float*)d_in[4];
  const float* Wm1  = (const float*)d_in[5];
  const float* bm1  = (const float*)d_in[6];
  const float* Wm2  = (const float*)d_in[7];
  const float* bm2  = (const float*)d_in[8];
  const float* Wu1  = (const float*)d_in[9];
  const float* bu1  = (const float*)d_in[10];
  const float* Wu2  = (const float*)d_in[11];
  const float* bu2  = (const float*)d_in[12];
  float* h = (float*)d_out;   // h state lives directly in d_out

  const size_t h2_bytes = (size_t)NN * HID * sizeof(unsigned);  // 4 MB
  const bool sent = ws_size >= h2_bytes;
  unsigned* h2u = (unsigned*)d_ws;
  int* flags    = (int*)d_ws;
  const int fs = sent ? 0 : ((ws_size >= (size_t)NN * 64 + 64) ? 16 : 1);

  k_h0<<<NN / 8, 128, 0, stream>>>(x, Wp, bp, h, h2u, flags, fs, sent ? 1 : 0);
  if (sent)
    k_dag<true><<<NBLK, 256, 0, stream>>>(ei, attr, Wm1, bm1, Wm2, bm2,
                                          Wu1, bu1, Wu2, bu2, h, h2u, flags, fs);
  else
    k_dag<false><<<NBLK, 256, 0, stream>>>(ei, attr, Wm1, bm1, Wm2, bm2,
                                           Wu1, bu1, Wu2, bu2, h, h2u, flags, fs);
}

// Round 7
// 556.128 us; speedup vs baseline: 5.9723x; 1.1445x over previous
//
#include <hip/hip_runtime.h>

#define NN   8192
#define DEG  16
#define HID  128
#define IND  128
#define ED   8
#define NBLK 256

typedef __bf16 bf16_t;
typedef __bf16 bf16x8 __attribute__((ext_vector_type(8)));
typedef float  f32x4  __attribute__((ext_vector_type(4)));
typedef unsigned long long u64;

static __device__ __forceinline__ f32x4 mfma16(bf16x8 a, bf16x8 b, f32x4 c) {
  return __builtin_amdgcn_mfma_f32_16x16x32_bf16(a, b, c, 0, 0, 0);
}
static __device__ __forceinline__ unsigned short bfbits(bf16_t x) {
  return __builtin_bit_cast(unsigned short, x);
}
static __device__ __forceinline__ bf16_t bits2bf(unsigned short x) {
  return __builtin_bit_cast(bf16_t, x);
}
// LDS-phase barrier: drain LDS ops only -- global loads/stores stay in flight.
static __device__ __forceinline__ void bar_lds() {
  __builtin_amdgcn_sched_barrier(0);
  asm volatile("s_waitcnt lgkmcnt(0)" ::: "memory");
  __builtin_amdgcn_s_barrier();
  __builtin_amdgcn_sched_barrier(0);
}
// full-drain barrier (used once, before the output tail)
static __device__ __forceinline__ void bar_full() {
  __builtin_amdgcn_sched_barrier(0);
  asm volatile("s_waitcnt vmcnt(0) lgkmcnt(0)" ::: "memory");
  __builtin_amdgcn_s_barrier();
  __builtin_amdgcn_sched_barrier(0);
}

// ---------------- kernel 1: h0 = x @ Wp + bp ; init sync state ----------------
__global__ __launch_bounds__(128) void k_h0(const float* __restrict__ x,
                                            const float* __restrict__ Wp,
                                            const float* __restrict__ bp,
                                            float* __restrict__ h,
                                            unsigned* __restrict__ h2u,
                                            int* __restrict__ flags, int fs,
                                            int sent) {
  __shared__ float sx[8][IND];
  const int t  = threadIdx.x;      // 0..127 = output channel
  const int vb = blockIdx.x * 8;   // 8 nodes per block
  #pragma unroll
  for (int rr = 0; rr < 8; ++rr) sx[rr][t] = x[(size_t)(vb + rr) * IND + t];
  __syncthreads();
  float acc[8];
  const float bias = bp[t];
  #pragma unroll
  for (int rr = 0; rr < 8; ++rr) acc[rr] = bias;
  for (int k = 0; k < IND; ++k) {
    const float w = Wp[k * HID + t];
    #pragma unroll
    for (int rr = 0; rr < 8; ++rr) acc[rr] += sx[rr][k] * w;
  }
  #pragma unroll
  for (int rr = 0; rr < 8; ++rr) h[(size_t)(vb + rr) * HID + t] = acc[rr];
  if (sent) {
    // h2: row 0 = packed hi/lo of h0 (node 0 final); rows >=1 = sentinel
    #pragma unroll
    for (int rr = 0; rr < 8; ++rr) {
      unsigned val = 0xFFFFFFFFu;
      if (vb + rr == 0) {
        const float f = acc[rr];
        const bf16_t fh = (bf16_t)f;
        const bf16_t fl = (bf16_t)(f - (float)fh);
        val = ((unsigned)bfbits(fh) << 16) | (unsigned)bfbits(fl);
      }
      h2u[(size_t)(vb + rr) * HID + t] = val;
    }
  } else if (t < 8) {
    flags[(vb + t) * fs] = (vb + t == 0) ? 0xF : 0;
  }
}

// ---------------- kernel 2: persistent DAG executor ----------------
// 256 blocks (1/CU, co-resident), 4 waves, each wave owns two ADJACENT
// channels per lane (cc = wid*32 + 2r, 2r+1) so publish = one u64 store.
// Precision plan: m1 full (hi + weight-lo + act-lo: recurrent transform),
// u2 hi + weight-lo (forms next state), m2 / u1-agg hi-only.
#define LOAD_WFRAGS(W, KROWS, NKK, ARRH, ARRL)                                \
  _Pragma("unroll")                                                           \
  for (int n = 0; n < 2; ++n) {                                               \
    _Pragma("unroll")                                                         \
    for (int kk = 0; kk < NKK; ++kk) {                                        \
      _Pragma("unroll")                                                       \
      for (int i = 0; i < 8; ++i) {                                           \
        const int k = kk * 32 + g * 8 + i;                                    \
        const float w = (k < KROWS) ? W[k * HID + cc[n]] : 0.f;               \
        const bf16_t wh = (bf16_t)w;                                          \
        ARRH[n][kk][i] = wh;                                                  \
        ARRL[n][kk][i] = (bf16_t)(w - (float)wh);                             \
      }                                                                       \
    }                                                                         \
  }
#define LOAD_WFRAGS_H(W, KROWS, NKK, ARRH)                                    \
  _Pragma("unroll")                                                           \
  for (int n = 0; n < 2; ++n) {                                               \
    _Pragma("unroll")                                                         \
    for (int kk = 0; kk < NKK; ++kk) {                                        \
      _Pragma("unroll")                                                       \
      for (int i = 0; i < 8; ++i) {                                           \
        const int k = kk * 32 + g * 8 + i;                                    \
        const float w = (k < KROWS) ? W[k * HID + cc[n]] : 0.f;               \
        ARRH[n][kk][i] = (bf16_t)w;                                           \
      }                                                                       \
    }                                                                         \
  }

#define LOADQ()                                                               \
  _Pragma("unroll")                                                           \
  for (int kk = 0; kk < 4; ++kk) {                                            \
    _Pragma("unroll")                                                         \
    for (int u = 0; u < 4; ++u)                                               \
      q[kk * 4 + u] = __hip_atomic_load(hp + kk * 16 + u, __ATOMIC_RELAXED,   \
                                        __HIP_MEMORY_SCOPE_AGENT);            \
  }

#define ZERO4(a) { a[0][0]=0.f;a[0][1]=0.f;a[0][2]=0.f;a[0][3]=0.f; a[1]=a[0]; }
#define BIAS4(a, b) { a[0][0]=b[0];a[0][1]=b[0];a[0][2]=b[0];a[0][3]=b[0];    \
                      a[1][0]=b[1];a[1][1]=b[1];a[1][2]=b[1];a[1][3]=b[1]; }

template <bool SENT>
__global__ __launch_bounds__(256, 1) void k_dag(
    const int* __restrict__ ei, const float* __restrict__ attr,
    const float* __restrict__ Wm1, const float* __restrict__ bm1,
    const float* __restrict__ Wm2, const float* __restrict__ bm2,
    const float* __restrict__ Wu1, const float* __restrict__ bu1,
    const float* __restrict__ Wu2, const float* __restrict__ bu2,
    float* __restrict__ h, unsigned* __restrict__ h2u,
    int* __restrict__ flags, int fs) {
  const int tid  = threadIdx.x;
  const int lane = tid & 63;
  const int g    = lane >> 4;   // 16-lane group: k-block of A/B operands
  const int r    = lane & 15;   // A-row / B-col within tile
  const int wid  = tid >> 6;    // wave 0..3

  __shared__ bf16_t s_m1[16 * HID];            // msg1 acts, chunk-XOR swizzled
  __shared__ alignas(16) bf16_t s_agg[HID];    // bf16: read directly as frags
  __shared__ alignas(16) bf16_t s_u1[HID];

  int cc[2];                     // two ADJACENT channels per lane
  cc[0] = wid * 32 + 2 * r;
  cc[1] = cc[0] + 1;

  // ---- register-resident weight fragments ----
  bf16x8 wm1h[2][5], wm1l[2][5];          // m1: full hi/lo
  bf16x8 wm2h[2][4];                      // m2: hi only
  bf16x8 wu1h[2][8], wu1l[2][4];          // u1: lo only for h-half (kk 0..3)
  bf16x8 wu2h[2][4], wu2l[2][4];          // u2: hi/lo
  LOAD_WFRAGS(Wm1, 136, 5, wm1h, wm1l)    // rows 0..127 = h, 128..135 = attr
  LOAD_WFRAGS_H(Wm2, 128, 4, wm2h)
  LOAD_WFRAGS_H(Wu1, 256, 8, wu1h)
  LOAD_WFRAGS(Wu1, 128, 4, wu1h /*dummy-overwritten-same*/, wu1l)
  LOAD_WFRAGS(Wu2, 128, 4, wu2h, wu2l)
  float bs_m1[2], bs_m2[2], bs_u1[2], bs_u2[2];
  #pragma unroll
  for (int n = 0; n < 2; ++n) {
    bs_m1[n] = bm1[cc[n]]; bs_m2[n] = bm2[cc[n]];
    bs_u1[n] = bu1[cc[n]]; bs_u2[n] = bu2[cc[n]];
  }

  const int v0 = 1 + (int)blockIdx.x;
  int s_cur = (v0 < NN) ? ei[(v0 - 1) * DEG + r] : 0;

  for (int v = v0; v < NN; v += NBLK) {
    // ---- poll/gather loads issue FIRST (minimize detect phase delay) ----
    u64 q[16];
    const u64* hp =
        (const u64*)((SENT ? (const void*)h2u : (const void*)h)) +
        (size_t)s_cur * (HID / 2) + g * 4;
    LOADQ();

    // ---- off-chain: next edge list, own h0 row -> fragments, attr frag ----
    const int vn = (v + NBLK < NN) ? v + NBLK : v;
    const int s_nxt = ei[(vn - 1) * DEG + r];

    bf16x8 hvh[4], hvl[4];
    {
      const float* hvp = h + (size_t)v * HID + g * 8;
      #pragma unroll
      for (int kk = 0; kk < 4; ++kk) {
        const f32x4 p0 = *(const f32x4*)(hvp + kk * 32);
        const f32x4 p1 = *(const f32x4*)(hvp + kk * 32 + 4);
        #pragma unroll
        for (int i = 0; i < 4; ++i) {
          const float f0 = p0[i], f1 = p1[i];
          const bf16_t f0h = (bf16_t)f0, f1h = (bf16_t)f1;
          hvh[kk][i]     = f0h; hvl[kk][i]     = (bf16_t)(f0 - (float)f0h);
          hvh[kk][4 + i] = f1h; hvl[kk][4 + i] = (bf16_t)(f1 - (float)f1h);
        }
      }
    }
    bf16x8 a4h;
    #pragma unroll
    for (int i = 0; i < 8; ++i) a4h[i] = (bf16_t)0.f;
    if (g == 0) {
      const f32x4* ap = (const f32x4*)(attr + ((size_t)(v - 1) * DEG + r) * ED);
      const f32x4 a0 = ap[0], a1 = ap[1];
      #pragma unroll
      for (int i = 0; i < 4; ++i) {
        a4h[i] = (bf16_t)a0[i]; a4h[4 + i] = (bf16_t)a1[i];
      }
    }

    // ---- off-chain MFMA work overlapping the in-flight poll loads ----
    // (a) u1 h0_v-half (hi + weight-lo + act-lo; off-chain so keep all)
    f32x4 uA[2], uB[2], uC[2], uD[2];
    BIAS4(uA, bs_u1) ZERO4(uB) ZERO4(uC) ZERO4(uD)
    #pragma unroll
    for (int kk = 0; kk < 4; ++kk) {
      #pragma unroll
      for (int n = 0; n < 2; ++n) {
        uA[n] = mfma16(hvh[kk], wu1h[n][kk], uA[n]);
        uB[n] = mfma16(hvh[kk], wu1l[n][kk], uB[n]);
        uC[n] = mfma16(hvl[kk], wu1h[n][kk], uC[n]);
      }
    }
    // (b) m1 init + attr k-step (independent of preds); 6 accumulators
    f32x4 mA[2], mB[2], mC[2], mD[2], mE[2], mF[2];
    BIAS4(mA, bs_m1) ZERO4(mB) ZERO4(mC) ZERO4(mD) ZERO4(mE) ZERO4(mF)
    #pragma unroll
    for (int n = 0; n < 2; ++n) {
      mA[n] = mfma16(a4h, wm1h[n][4], mA[n]);
      mB[n] = mfma16(a4h, wm1l[n][4], mB[n]);
    }

    // ---- spin: data IS the sync (bit31 of each packed u32 = sentinel) ----
    if constexpr (SENT) {
      bool ok = false;
      int guard = 0;
      for (;;) {
        if (!ok) {
          u64 m = 0;
          #pragma unroll
          for (int i = 0; i < 16; ++i) m |= q[i];
          ok = (s_cur == 0) || ((m & 0x8000000080000000ull) == 0);
        }
        if (__all(ok)) break;
        if (++guard > (1 << 13)) break;  // fail-safe: wrong answer, never hang
        if (!ok) LOADQ();
      }
    } else {
      const int* fp = flags + s_cur * fs;
      int fw = __hip_atomic_load(fp, __ATOMIC_RELAXED, __HIP_MEMORY_SCOPE_AGENT);
      int guard = 0;
      while (fw != 0xF && ++guard < (1 << 15)) {
        __builtin_amdgcn_s_sleep(1);
        fw = __hip_atomic_load(fp, __ATOMIC_RELAXED, __HIP_MEMORY_SCOPE_AGENT);
      }
      asm volatile("" ::: "memory");  // gathers stay below the spin
      LOADQ();
    }

    // ---- A fragments: SENT = pure bit-split; fallback = f32 convert ----
    bf16x8 ah[4], al[4];
    #pragma unroll
    for (int kk = 0; kk < 4; ++kk) {
      #pragma unroll
      for (int u = 0; u < 4; ++u) {
        #pragma unroll
        for (int b = 0; b < 2; ++b) {
          const unsigned w = (unsigned)(q[kk * 4 + u] >> (32 * b));
          if constexpr (SENT) {
            ah[kk][u * 2 + b] = bits2bf((unsigned short)(w >> 16));
            al[kk][u * 2 + b] = bits2bf((unsigned short)(w & 0xFFFFu));
          } else {
            const float f = __uint_as_float(w);
            const bf16_t fh = (bf16_t)f;
            ah[kk][u * 2 + b] = fh;
            al[kk][u * 2 + b] = (bf16_t)(f - (float)fh);
          }
        }
      }
    }

    // ---- msg layer 1: 4 pred k-steps, depth-2 chains, full precision ----
    f32x4 m1[2];
    #pragma unroll
    for (int kk = 0; kk < 2; ++kk) {
      #pragma unroll
      for (int n = 0; n < 2; ++n) {
        mA[n] = mfma16(ah[kk], wm1h[n][kk], mA[n]);
        mB[n] = mfma16(ah[kk], wm1l[n][kk], mB[n]);
        mC[n] = mfma16(al[kk], wm1h[n][kk], mC[n]);
        mD[n] = mfma16(ah[kk + 2], wm1h[n][kk + 2], mD[n]);
        mE[n] = mfma16(ah[kk + 2], wm1l[n][kk + 2], mE[n]);
        mF[n] = mfma16(al[kk + 2], wm1h[n][kk + 2], mF[n]);
      }
    }
    #pragma unroll
    for (int n = 0; n < 2; ++n)
      m1[n] = ((mA[n] + mB[n]) + (mC[n] + mD[n])) + (mE[n] + mF[n]);
    // relu -> bf16 -> LDS with chunk-XOR swizzle (conflict-free b128 reads)
    #pragma unroll
    for (int n = 0; n < 2; ++n) {
      const int c = cc[n], ch16 = c >> 3;
      #pragma unroll
      for (int reg = 0; reg < 4; ++reg) {
        const int j = g * 4 + reg;  // edge row (D layout: row = 4*(lane>>4)+reg)
        s_m1[j * HID + ((ch16 ^ j) * 8) + (c & 7)] = (bf16_t)fmaxf(m1[n][reg], 0.f);
      }
    }
    if constexpr (SENT) bar_lds(); else __syncthreads();   // B1

    // ---- msg layer 2 (hi-only) + mean aggregation ----
    f32x4 m2[2];
    {
      f32x4 aA[2], aC[2];
      BIAS4(aA, bs_m2) ZERO4(aC)
      #pragma unroll
      for (int kk = 0; kk < 2; ++kk) {
        const int ph0 = (kk * 4 + g) ^ r;
        const int ph1 = ((kk + 2) * 4 + g) ^ r;
        const bf16x8 a0 = *(const bf16x8*)(s_m1 + r * HID + ph0 * 8);
        const bf16x8 a1 = *(const bf16x8*)(s_m1 + r * HID + ph1 * 8);
        #pragma unroll
        for (int n = 0; n < 2; ++n) {
          aA[n] = mfma16(a0, wm2h[n][kk], aA[n]);
          aC[n] = mfma16(a1, wm2h[n][kk + 2], aC[n]);
        }
      }
      #pragma unroll
      for (int n = 0; n < 2; ++n) m2[n] = aA[n] + aC[n];
    }
    #pragma unroll
    for (int n = 0; n < 2; ++n) {
      float s = fmaxf(m2[n][0],0.f)+fmaxf(m2[n][1],0.f)+fmaxf(m2[n][2],0.f)+fmaxf(m2[n][3],0.f);
      s += __shfl_xor(s, 16, 64);
      s += __shfl_xor(s, 32, 64);
      if (lane < 16) s_agg[cc[n]] = (bf16_t)(s * 0.0625f);  // bf16 once
    }
    if constexpr (SENT) bar_lds(); else __syncthreads();   // B2

    // ---- update layer 1, agg-half (hi-only, depth-2: kk45 -> uA, kk67 -> uD) ----
    f32x4 u1v[2];
    #pragma unroll
    for (int kk = 4; kk < 6; ++kk) {
      const bf16x8 Ah0 = *(const bf16x8*)(s_agg + (kk - 4) * 32 + g * 8);
      const bf16x8 Ah1 = *(const bf16x8*)(s_agg + (kk - 2) * 32 + g * 8);
      #pragma unroll
      for (int n = 0; n < 2; ++n) {
        uA[n] = mfma16(Ah0, wu1h[n][kk], uA[n]);
        uD[n] = mfma16(Ah1, wu1h[n][kk + 2], uD[n]);
      }
    }
    #pragma unroll
    for (int n = 0; n < 2; ++n)
      u1v[n] = (uA[n] + uB[n]) + (uC[n] + uD[n]);
    if (lane < 16) {
      s_u1[cc[0]] = (bf16_t)fmaxf(u1v[0][0], 0.f);
      s_u1[cc[1]] = (bf16_t)fmaxf(u1v[1][0], 0.f);
    }
    if constexpr (SENT) bar_lds(); else __syncthreads();   // B3

    // ---- update layer 2 (hi + weight-lo) -> publish ----
    f32x4 u2v[2];
    {
      f32x4 aA[2], aB[2], aC[2], aD[2];
      BIAS4(aA, bs_u2) ZERO4(aB) ZERO4(aC) ZERO4(aD)
      #pragma unroll
      for (int kk = 0; kk < 2; ++kk) {
        const bf16x8 Ah0 = *(const bf16x8*)(s_u1 + kk * 32 + g * 8);
        const bf16x8 Ah1 = *(const bf16x8*)(s_u1 + (kk + 2) * 32 + g * 8);
        #pragma unroll
        for (int n = 0; n < 2; ++n) {
          aA[n] = mfma16(Ah0, wu2h[n][kk], aA[n]);
          aB[n] = mfma16(Ah0, wu2l[n][kk], aB[n]);
          aC[n] = mfma16(Ah1, wu2h[n][kk + 2], aC[n]);
          aD[n] = mfma16(Ah1, wu2l[n][kk + 2], aD[n]);
        }
      }
      #pragma unroll
      for (int n = 0; n < 2; ++n) u2v[n] = (aA[n] + aB[n]) + (aC[n] + aD[n]);
    }
    if (lane < 16) {  // D row 0 (all rows identical)
      if constexpr (SENT) {
        // channels cc[0], cc[0]+1 adjacent: ONE u64 packed store
        u64 pp = 0;
        #pragma unroll
        for (int n = 0; n < 2; ++n) {
          const float rv = fabsf(fmaxf(u2v[n][0], 0.f));  // fabs: kill -0.0
          const bf16_t rh = (bf16_t)rv;
          const bf16_t rl = (bf16_t)(rv - (float)rh);
          const unsigned pw = ((unsigned)bfbits(rh) << 16) | (unsigned)bfbits(rl);
          pp |= (u64)pw << (32 * n);
        }
        __hip_atomic_store((u64*)&h2u[(size_t)v * HID + cc[0]], pp,
                           __ATOMIC_RELAXED, __HIP_MEMORY_SCOPE_AGENT);
      } else {
        #pragma unroll
        for (int n = 0; n < 2; ++n) {
          const float rv = fabsf(fmaxf(u2v[n][0], 0.f));
          __hip_atomic_store(&h[(size_t)v * HID + cc[n]], rv,
                             __ATOMIC_RELAXED, __HIP_MEMORY_SCOPE_AGENT);
        }
      }
    }
    if constexpr (!SENT) {
      if (lane == 0)
        __hip_atomic_fetch_or(&flags[v * fs], 1 << wid, __ATOMIC_RELEASE,
                              __HIP_MEMORY_SCOPE_AGENT);
    }
    s_cur = s_nxt;
    if constexpr (!SENT) __syncthreads();
  }

  // ---- output tail: reconstruct fp32 h rows from h2 (off critical chain) ----
  if constexpr (SENT) {
    bar_full();  // own h2 stores must be MALL-visible before re-read
    const int half = tid >> 7;          // 0/1: two nodes per iteration
    const int c    = tid & 127;
    #pragma unroll 4
    for (int v = v0 + half * NBLK; v < NN; v += 2 * NBLK) {
      const unsigned w = __hip_atomic_load(&h2u[(size_t)v * HID + c],
                                           __ATOMIC_RELAXED,
                                           __HIP_MEMORY_SCOPE_AGENT);
      h[(size_t)v * HID + c] =
          (float)bits2bf((unsigned short)(w >> 16)) +
          (float)bits2bf((unsigned short)(w & 0xFFFFu));
    }
  }
}

extern "C" void kernel_launch(void* const* d_in, const int* in_sizes, int n_in,
                              void* d_out, int out_size, void* d_ws, size_t ws_size,
                              hipStream_t stream) {
  const float* x    = (const float*)d_in[0];
  const int*   ei   = (const int*)  d_in[1];   // [2, E] int32; row 0 = src
  const float* attr = (const float*)d_in[2];
  const float* Wp   = (const float*)d_in[3];
  const float* bp   = (const float*)d_in[4];
  const float* Wm1  = (const float*)d_in[5];
  const float* bm1  = (const float*)d_in[6];
  const float* Wm2  = (const float*)d_in[7];
  const float* bm2  = (const float*)d_in[8];
  const float* Wu1  = (const float*)d_in[9];
  const float* bu1  = (const float*)d_in[10];
  const float* Wu2  = (const float*)d_in[11];
  const float* bu2  = (const float*)d_in[12];
  float* h = (float*)d_out;   // h state lives directly in d_out

  const size_t h2_bytes = (size_t)NN * HID * sizeof(unsigned);  // 4 MB
  const bool sent = ws_size >= h2_bytes;
  unsigned* h2u = (unsigned*)d_ws;
  int* flags    = (int*)d_ws;
  const int fs = sent ? 0 : ((ws_size >= (size_t)NN * 64 + 64) ? 16 : 1);

  k_h0<<<NN / 8, 128, 0, stream>>>(x, Wp, bp, h, h2u, flags, fs, sent ? 1 : 0);
  if (sent)
    k_dag<true><<<NBLK, 256, 0, stream>>>(ei, attr, Wm1, bm1, Wm2, bm2,
                                          Wu1, bu1, Wu2, bu2, h, h2u, flags, fs);
  else
    k_dag<false><<<NBLK, 256, 0, stream>>>(ei, attr, Wm1, bm1, Wm2, bm2,
                                           Wu1, bu1, Wu2, bu2, h, h2u, flags, fs);
}

// Round 8
// 508.469 us; speedup vs baseline: 6.5321x; 1.0937x over previous
//
#include <hip/hip_runtime.h>

#define NN   8192
#define DEG  16
#define HID  128
#define IND  128
#define ED   8
#define NBLK 256

typedef __bf16 bf16_t;
typedef __bf16 bf16x8 __attribute__((ext_vector_type(8)));
typedef float  f32x4  __attribute__((ext_vector_type(4)));
typedef unsigned long long u64;
typedef u64 u64x2 __attribute__((ext_vector_type(2)));

static __device__ __forceinline__ f32x4 mfma16(bf16x8 a, bf16x8 b, f32x4 c) {
  return __builtin_amdgcn_mfma_f32_16x16x32_bf16(a, b, c, 0, 0, 0);
}
static __device__ __forceinline__ unsigned short bfbits(bf16_t x) {
  return __builtin_bit_cast(unsigned short, x);
}
static __device__ __forceinline__ bf16_t bits2bf(unsigned short x) {
  return __builtin_bit_cast(bf16_t, x);
}
// LDS-phase barrier: drain LDS ops only -- global loads/stores stay in flight.
static __device__ __forceinline__ void bar_lds() {
  __builtin_amdgcn_sched_barrier(0);
  asm volatile("s_waitcnt lgkmcnt(0)" ::: "memory");
  __builtin_amdgcn_s_barrier();
  __builtin_amdgcn_sched_barrier(0);
}
// full-drain barrier (used once, before the output tail)
static __device__ __forceinline__ void bar_full() {
  __builtin_amdgcn_sched_barrier(0);
  asm volatile("s_waitcnt vmcnt(0) lgkmcnt(0)" ::: "memory");
  __builtin_amdgcn_s_barrier();
  __builtin_amdgcn_sched_barrier(0);
}

// ---------------- kernel 1: h0 = x @ Wp + bp ; init sync state ----------------
__global__ __launch_bounds__(128) void k_h0(const float* __restrict__ x,
                                            const float* __restrict__ Wp,
                                            const float* __restrict__ bp,
                                            float* __restrict__ h,
                                            bf16_t* __restrict__ h2hi,
                                            bf16_t* __restrict__ h2lo,
                                            int* __restrict__ flags, int fs,
                                            int sent) {
  __shared__ float sx[8][IND];
  const int t  = threadIdx.x;      // 0..127 = output channel
  const int vb = blockIdx.x * 8;   // 8 nodes per block
  #pragma unroll
  for (int rr = 0; rr < 8; ++rr) sx[rr][t] = x[(size_t)(vb + rr) * IND + t];
  __syncthreads();
  float acc[8];
  const float bias = bp[t];
  #pragma unroll
  for (int rr = 0; rr < 8; ++rr) acc[rr] = bias;
  for (int k = 0; k < IND; ++k) {
    const float w = Wp[k * HID + t];
    #pragma unroll
    for (int rr = 0; rr < 8; ++rr) acc[rr] += sx[rr][k] * w;
  }
  #pragma unroll
  for (int rr = 0; rr < 8; ++rr) h[(size_t)(vb + rr) * HID + t] = acc[rr];
  if (sent) {
    // hi plane: row 0 = bf16-hi of h0 (node 0 final); rows >=1 = 0xFFFF sentinel
    #pragma unroll
    for (int rr = 0; rr < 8; ++rr) {
      unsigned short hw = 0xFFFFu, lw = 0xFFFFu;
      if (vb + rr == 0) {
        const float f = acc[rr];
        const bf16_t fh = (bf16_t)f;
        hw = bfbits(fh);
        lw = bfbits((bf16_t)(f - (float)fh));
      }
      h2hi[(size_t)(vb + rr) * HID + t] = bits2bf(hw);
      h2lo[(size_t)(vb + rr) * HID + t] = bits2bf(lw);
    }
  } else if (t < 8) {
    flags[(vb + t) * fs] = (vb + t == 0) ? 0xF : 0;
  }
}

// ---------------- kernel 2: persistent DAG executor ----------------
// 256 blocks (1/CU), 4 waves, each wave owns two ADJACENT channels per lane
// (cc = wid*32+2r, +1). Sync channel = PLANAR bf16-hi rows: the gathered 16B
// chunks ARE the MFMA A-fragments (zero unpack on the chain); sentinel =
// bf16 sign bits (0xFFFF fill). m1 consumes hi-only (act-lo dropped; R5/R7
// evidence: each act-quant point costs x2 absmax once, no compounding).
#define LOAD_WFRAGS(W, KROWS, NKK, ARRH, ARRL)                                \
  _Pragma("unroll")                                                           \
  for (int n = 0; n < 2; ++n) {                                               \
    _Pragma("unroll")                                                         \
    for (int kk = 0; kk < NKK; ++kk) {                                        \
      _Pragma("unroll")                                                       \
      for (int i = 0; i < 8; ++i) {                                           \
        const int k = kk * 32 + g * 8 + i;                                    \
        const float w = (k < KROWS) ? W[k * HID + cc[n]] : 0.f;               \
        const bf16_t wh = (bf16_t)w;                                          \
        ARRH[n][kk][i] = wh;                                                  \
        ARRL[n][kk][i] = (bf16_t)(w - (float)wh);                             \
      }                                                                       \
    }                                                                         \
  }
#define LOAD_WFRAGS_H(W, KROWS, NKK, ARRH)                                    \
  _Pragma("unroll")                                                           \
  for (int n = 0; n < 2; ++n) {                                               \
    _Pragma("unroll")                                                         \
    for (int kk = 0; kk < NKK; ++kk) {                                        \
      _Pragma("unroll")                                                       \
      for (int i = 0; i < 8; ++i) {                                           \
        const int k = kk * 32 + g * 8 + i;                                    \
        const float w = (k < KROWS) ? W[k * HID + cc[n]] : 0.f;               \
        ARRH[n][kk][i] = (bf16_t)w;                                           \
      }                                                                       \
    }                                                                         \
  }
#define LOAD_WFRAGS_L(W, KROWS, NKK, ARRL)                                    \
  _Pragma("unroll")                                                           \
  for (int n = 0; n < 2; ++n) {                                               \
    _Pragma("unroll")                                                         \
    for (int kk = 0; kk < NKK; ++kk) {                                        \
      _Pragma("unroll")                                                       \
      for (int i = 0; i < 8; ++i) {                                           \
        const int k = kk * 32 + g * 8 + i;                                    \
        const float w = (k < KROWS) ? W[k * HID + cc[n]] : 0.f;               \
        ARRL[n][kk][i] = (bf16_t)(w - (float)(bf16_t)w);                      \
      }                                                                       \
    }                                                                         \
  }

// SENT gather: 8 u64 relaxed-atomic loads of the hi plane (lane's quarter row)
#define LOADQH()                                                              \
  _Pragma("unroll")                                                           \
  for (int kk = 0; kk < 4; ++kk) {                                            \
    _Pragma("unroll")                                                         \
    for (int u = 0; u < 2; ++u)                                               \
      q[kk * 2 + u] = __hip_atomic_load(hp + kk * 8 + u, __ATOMIC_RELAXED,    \
                                        __HIP_MEMORY_SCOPE_AGENT);            \
  }

#define ZERO4(a) { a[0][0]=0.f;a[0][1]=0.f;a[0][2]=0.f;a[0][3]=0.f; a[1]=a[0]; }
#define BIAS4(a, b) { a[0][0]=b[0];a[0][1]=b[0];a[0][2]=b[0];a[0][3]=b[0];    \
                      a[1][0]=b[1];a[1][1]=b[1];a[1][2]=b[1];a[1][3]=b[1]; }

template <bool SENT>
__global__ __launch_bounds__(256, 1) void k_dag(
    const int* __restrict__ ei, const float* __restrict__ attr,
    const float* __restrict__ Wm1, const float* __restrict__ bm1,
    const float* __restrict__ Wm2, const float* __restrict__ bm2,
    const float* __restrict__ Wu1, const float* __restrict__ bu1,
    const float* __restrict__ Wu2, const float* __restrict__ bu2,
    float* __restrict__ h, bf16_t* __restrict__ h2hi,
    bf16_t* __restrict__ h2lo, int* __restrict__ flags, int fs) {
  const int tid  = threadIdx.x;
  const int lane = tid & 63;
  const int g    = lane >> 4;   // 16-lane group: k-block of A/B operands
  const int r    = lane & 15;   // A-row / B-col within tile
  const int wid  = tid >> 6;    // wave 0..3

  __shared__ bf16_t s_m1[16 * HID];            // msg1 acts, chunk-XOR swizzled
  __shared__ alignas(16) bf16_t s_agg[HID];    // bf16: read directly as frags
  __shared__ alignas(16) bf16_t s_u1[HID];

  int cc[2];                     // two ADJACENT channels per lane
  cc[0] = wid * 32 + 2 * r;
  cc[1] = cc[0] + 1;

  // ---- register-resident weight fragments ----
  bf16x8 wm1h[2][5], wm1l[2][5];          // m1: hi + weight-lo (act-lo dropped)
  bf16x8 wm2h[2][4];                      // m2: hi only
  bf16x8 wu1h[2][8], wu1l[2][4];          // u1: lo only for h-half (kk 0..3)
  bf16x8 wu2h[2][4], wu2l[2][4];          // u2: hi/lo
  LOAD_WFRAGS(Wm1, 136, 5, wm1h, wm1l)    // rows 0..127 = h, 128..135 = attr
  LOAD_WFRAGS_H(Wm2, 128, 4, wm2h)
  LOAD_WFRAGS_H(Wu1, 256, 8, wu1h)
  LOAD_WFRAGS_L(Wu1, 128, 4, wu1l)
  LOAD_WFRAGS(Wu2, 128, 4, wu2h, wu2l)
  float bs_m1[2], bs_m2[2], bs_u1[2], bs_u2[2];
  #pragma unroll
  for (int n = 0; n < 2; ++n) {
    bs_m1[n] = bm1[cc[n]]; bs_m2[n] = bm2[cc[n]];
    bs_u1[n] = bu1[cc[n]]; bs_u2[n] = bu2[cc[n]];
  }

  const int v0 = 1 + (int)blockIdx.x;
  int s_cur = (v0 < NN) ? ei[(v0 - 1) * DEG + r] : 0;

  for (int v = v0; v < NN; v += NBLK) {
    // ---- poll/gather loads issue FIRST (minimize detect phase delay) ----
    u64 q[16];  // SENT uses [0..7] (hi plane); fallback uses all 16 (fp32 row)
    const u64* hp;
    if constexpr (SENT) {
      hp = (const u64*)(h2hi + (size_t)s_cur * HID) + g * 2;  // 32 u64/row
      LOADQH();
    } else {
      hp = (const u64*)(h + (size_t)s_cur * HID) + g * 4;
      #pragma unroll
      for (int kk = 0; kk < 4; ++kk)
        #pragma unroll
        for (int u = 0; u < 4; ++u)
          q[kk * 4 + u] = __hip_atomic_load(hp + kk * 16 + u, __ATOMIC_RELAXED,
                                            __HIP_MEMORY_SCOPE_AGENT);
    }

    // ---- off-chain: next edge list, own h0 row -> fragments, attr frag ----
    const int vn = (v + NBLK < NN) ? v + NBLK : v;
    const int s_nxt = ei[(vn - 1) * DEG + r];

    bf16x8 hvh[4], hvl[4];
    {
      const float* hvp = h + (size_t)v * HID + g * 8;
      #pragma unroll
      for (int kk = 0; kk < 4; ++kk) {
        const f32x4 p0 = *(const f32x4*)(hvp + kk * 32);
        const f32x4 p1 = *(const f32x4*)(hvp + kk * 32 + 4);
        #pragma unroll
        for (int i = 0; i < 4; ++i) {
          const float f0 = p0[i], f1 = p1[i];
          const bf16_t f0h = (bf16_t)f0, f1h = (bf16_t)f1;
          hvh[kk][i]     = f0h; hvl[kk][i]     = (bf16_t)(f0 - (float)f0h);
          hvh[kk][4 + i] = f1h; hvl[kk][4 + i] = (bf16_t)(f1 - (float)f1h);
        }
      }
    }
    bf16x8 a4h;
    #pragma unroll
    for (int i = 0; i < 8; ++i) a4h[i] = (bf16_t)0.f;
    if (g == 0) {
      const f32x4* ap = (const f32x4*)(attr + ((size_t)(v - 1) * DEG + r) * ED);
      const f32x4 a0 = ap[0], a1 = ap[1];
      #pragma unroll
      for (int i = 0; i < 4; ++i) {
        a4h[i] = (bf16_t)a0[i]; a4h[4 + i] = (bf16_t)a1[i];
      }
    }

    // ---- off-chain MFMA work overlapping the in-flight poll loads ----
    // (a) u1 h0_v-half (hi + weight-lo + act-lo; off-chain so keep all)
    f32x4 uA[2], uB[2], uC[2], uD[2];
    BIAS4(uA, bs_u1) ZERO4(uB) ZERO4(uC) ZERO4(uD)
    #pragma unroll
    for (int kk = 0; kk < 4; ++kk) {
      #pragma unroll
      for (int n = 0; n < 2; ++n) {
        uA[n] = mfma16(hvh[kk], wu1h[n][kk], uA[n]);
        uB[n] = mfma16(hvh[kk], wu1l[n][kk], uB[n]);
        uC[n] = mfma16(hvl[kk], wu1h[n][kk], uC[n]);
      }
    }
    // (b) m1 init + attr k-step (independent of preds); 4 accumulators
    f32x4 mA[2], mB[2], mD[2], mE[2];
    BIAS4(mA, bs_m1) ZERO4(mB) ZERO4(mD) ZERO4(mE)
    #pragma unroll
    for (int n = 0; n < 2; ++n) {
      mA[n] = mfma16(a4h, wm1h[n][4], mA[n]);
      mB[n] = mfma16(a4h, wm1l[n][4], mB[n]);
    }

    // ---- spin: data IS the sync (bf16 sign bits = sentinel) ----
    if constexpr (SENT) {
      bool ok = false;
      int guard = 0;
      for (;;) {
        if (!ok) {
          u64 m = 0;
          #pragma unroll
          for (int i = 0; i < 8; ++i) m |= q[i];
          ok = (s_cur == 0) || ((m & 0x8000800080008000ull) == 0);
        }
        if (__all(ok)) break;
        if (++guard > (1 << 13)) break;  // fail-safe: wrong answer, never hang
        if (!ok) LOADQH();
      }
    } else {
      const int* fp = flags + s_cur * fs;
      int fw = __hip_atomic_load(fp, __ATOMIC_RELAXED, __HIP_MEMORY_SCOPE_AGENT);
      int guard = 0;
      while (fw != 0xF && ++guard < (1 << 15)) {
        __builtin_amdgcn_s_sleep(1);
        fw = __hip_atomic_load(fp, __ATOMIC_RELAXED, __HIP_MEMORY_SCOPE_AGENT);
      }
      asm volatile("" ::: "memory");
      #pragma unroll
      for (int kk = 0; kk < 4; ++kk)
        #pragma unroll
        for (int u = 0; u < 4; ++u)
          q[kk * 4 + u] = __hip_atomic_load(hp + kk * 16 + u, __ATOMIC_RELAXED,
                                            __HIP_MEMORY_SCOPE_AGENT);
    }

    // ---- A fragments: SENT = loaded 16B chunks verbatim (zero unpack) ----
    bf16x8 ah[4];
    #pragma unroll
    for (int kk = 0; kk < 4; ++kk) {
      if constexpr (SENT) {
        u64x2 t2; t2[0] = q[kk * 2]; t2[1] = q[kk * 2 + 1];
        ah[kk] = __builtin_bit_cast(bf16x8, t2);
      } else {
        #pragma unroll
        for (int u = 0; u < 4; ++u)
          #pragma unroll
          for (int b = 0; b < 2; ++b)
            ah[kk][u * 2 + b] =
                (bf16_t)__uint_as_float((unsigned)(q[kk * 4 + u] >> (32 * b)));
      }
    }

    // ---- msg layer 1: 4 pred k-steps, depth-2 chains (hi + weight-lo) ----
    f32x4 m1[2];
    #pragma unroll
    for (int kk = 0; kk < 2; ++kk) {
      #pragma unroll
      for (int n = 0; n < 2; ++n) {
        mA[n] = mfma16(ah[kk], wm1h[n][kk], mA[n]);
        mB[n] = mfma16(ah[kk], wm1l[n][kk], mB[n]);
        mD[n] = mfma16(ah[kk + 2], wm1h[n][kk + 2], mD[n]);
        mE[n] = mfma16(ah[kk + 2], wm1l[n][kk + 2], mE[n]);
      }
    }
    #pragma unroll
    for (int n = 0; n < 2; ++n) m1[n] = (mA[n] + mB[n]) + (mD[n] + mE[n]);
    // relu -> bf16 -> LDS with chunk-XOR swizzle (conflict-free b128 reads)
    #pragma unroll
    for (int n = 0; n < 2; ++n) {
      const int c = cc[n], ch16 = c >> 3;
      #pragma unroll
      for (int reg = 0; reg < 4; ++reg) {
        const int j = g * 4 + reg;  // edge row (D layout: row = 4*(lane>>4)+reg)
        s_m1[j * HID + ((ch16 ^ j) * 8) + (c & 7)] = (bf16_t)fmaxf(m1[n][reg], 0.f);
      }
    }
    if constexpr (SENT) bar_lds(); else __syncthreads();   // B1

    // ---- msg layer 2 (hi-only) + mean aggregation ----
    f32x4 m2[2];
    {
      f32x4 aA[2], aC[2];
      BIAS4(aA, bs_m2) ZERO4(aC)
      #pragma unroll
      for (int kk = 0; kk < 2; ++kk) {
        const int ph0 = (kk * 4 + g) ^ r;
        const int ph1 = ((kk + 2) * 4 + g) ^ r;
        const bf16x8 a0 = *(const bf16x8*)(s_m1 + r * HID + ph0 * 8);
        const bf16x8 a1 = *(const bf16x8*)(s_m1 + r * HID + ph1 * 8);
        #pragma unroll
        for (int n = 0; n < 2; ++n) {
          aA[n] = mfma16(a0, wm2h[n][kk], aA[n]);
          aC[n] = mfma16(a1, wm2h[n][kk + 2], aC[n]);
        }
      }
      #pragma unroll
      for (int n = 0; n < 2; ++n) m2[n] = aA[n] + aC[n];
    }
    #pragma unroll
    for (int n = 0; n < 2; ++n) {
      float s = fmaxf(m2[n][0],0.f)+fmaxf(m2[n][1],0.f)+fmaxf(m2[n][2],0.f)+fmaxf(m2[n][3],0.f);
      s += __shfl_xor(s, 16, 64);
      s += __shfl_xor(s, 32, 64);
      if (lane < 16) s_agg[cc[n]] = (bf16_t)(s * 0.0625f);  // bf16 once
    }
    if constexpr (SENT) bar_lds(); else __syncthreads();   // B2

    // ---- update layer 1, agg-half (hi-only, depth-2) ----
    f32x4 u1v[2];
    #pragma unroll
    for (int kk = 4; kk < 6; ++kk) {
      const bf16x8 Ah0 = *(const bf16x8*)(s_agg + (kk - 4) * 32 + g * 8);
      const bf16x8 Ah1 = *(const bf16x8*)(s_agg + (kk - 2) * 32 + g * 8);
      #pragma unroll
      for (int n = 0; n < 2; ++n) {
        uA[n] = mfma16(Ah0, wu1h[n][kk], uA[n]);
        uD[n] = mfma16(Ah1, wu1h[n][kk + 2], uD[n]);
      }
    }
    #pragma unroll
    for (int n = 0; n < 2; ++n)
      u1v[n] = (uA[n] + uB[n]) + (uC[n] + uD[n]);
    if (lane < 16) {
      s_u1[cc[0]] = (bf16_t)fmaxf(u1v[0][0], 0.f);
      s_u1[cc[1]] = (bf16_t)fmaxf(u1v[1][0], 0.f);
    }
    if constexpr (SENT) bar_lds(); else __syncthreads();   // B3

    // ---- update layer 2 (hi + weight-lo) -> publish ----
    f32x4 u2v[2];
    {
      f32x4 aA[2], aB[2], aC[2], aD[2];
      BIAS4(aA, bs_u2) ZERO4(aB) ZERO4(aC) ZERO4(aD)
      #pragma unroll
      for (int kk = 0; kk < 2; ++kk) {
        const bf16x8 Ah0 = *(const bf16x8*)(s_u1 + kk * 32 + g * 8);
        const bf16x8 Ah1 = *(const bf16x8*)(s_u1 + (kk + 2) * 32 + g * 8);
        #pragma unroll
        for (int n = 0; n < 2; ++n) {
          aA[n] = mfma16(Ah0, wu2h[n][kk], aA[n]);
          aB[n] = mfma16(Ah0, wu2l[n][kk], aB[n]);
          aC[n] = mfma16(Ah1, wu2h[n][kk + 2], aC[n]);
          aD[n] = mfma16(Ah1, wu2l[n][kk + 2], aD[n]);
        }
      }
      #pragma unroll
      for (int n = 0; n < 2; ++n) u2v[n] = (aA[n] + aB[n]) + (aC[n] + aD[n]);
    }
    if (lane < 16) {  // D row 0 (all rows identical)
      if constexpr (SENT) {
        const float r0 = fabsf(fmaxf(u2v[0][0], 0.f));  // fabs: kill -0.0
        const float r1 = fabsf(fmaxf(u2v[1][0], 0.f));
        const bf16_t h0b = (bf16_t)r0, h1b = (bf16_t)r1;
        // channels (2r, 2r+1): u32 at index wid*16+r of each plane row
        const unsigned hiw = (unsigned)bfbits(h0b) | ((unsigned)bfbits(h1b) << 16);
        const unsigned low = (unsigned)bfbits((bf16_t)(r0 - (float)h0b)) |
                             ((unsigned)bfbits((bf16_t)(r1 - (float)h1b)) << 16);
        const size_t wi = (size_t)v * (HID / 2) + wid * 16 + r;
        __hip_atomic_store((unsigned*)h2lo + wi, low,
                           __ATOMIC_RELAXED, __HIP_MEMORY_SCOPE_AGENT);
        __hip_atomic_store((unsigned*)h2hi + wi, hiw,
                           __ATOMIC_RELAXED, __HIP_MEMORY_SCOPE_AGENT);
      } else {
        #pragma unroll
        for (int n = 0; n < 2; ++n) {
          const float rv = fabsf(fmaxf(u2v[n][0], 0.f));
          __hip_atomic_store(&h[(size_t)v * HID + cc[n]], rv,
                             __ATOMIC_RELAXED, __HIP_MEMORY_SCOPE_AGENT);
        }
      }
    }
    if constexpr (!SENT) {
      if (lane == 0)
        __hip_atomic_fetch_or(&flags[v * fs], 1 << wid, __ATOMIC_RELEASE,
                              __HIP_MEMORY_SCOPE_AGENT);
    }
    s_cur = s_nxt;
    if constexpr (!SENT) __syncthreads();
  }

  // ---- output tail: reconstruct fp32 h = hi+lo (off critical chain) ----
  if constexpr (SENT) {
    bar_full();  // own plane stores must be MALL-visible before re-read
    const unsigned* hi32 = (const unsigned*)h2hi;
    const unsigned* lo32 = (const unsigned*)h2lo;
    const int sub = tid >> 6;     // 4 nodes per iteration, 64 lanes each
    const int c2  = tid & 63;     // u32 (channel-pair) index within row
    for (int v = v0 + sub * NBLK; v < NN; v += 4 * NBLK) {
      const unsigned hw = __hip_atomic_load(&hi32[(size_t)v * 64 + c2],
                                            __ATOMIC_RELAXED,
                                            __HIP_MEMORY_SCOPE_AGENT);
      const unsigned lw = __hip_atomic_load(&lo32[(size_t)v * 64 + c2],
                                            __ATOMIC_RELAXED,
                                            __HIP_MEMORY_SCOPE_AGENT);
      h[(size_t)v * HID + 2 * c2] =
          (float)bits2bf((unsigned short)(hw & 0xFFFF)) +
          (float)bits2bf((unsigned short)(lw & 0xFFFF));
      h[(size_t)v * HID + 2 * c2 + 1] =
          (float)bits2bf((unsigned short)(hw >> 16)) +
          (float)bits2bf((unsigned short)(lw >> 16));
    }
  }
}

extern "C" void kernel_launch(void* const* d_in, const int* in_sizes, int n_in,
                              void* d_out, int out_size, void* d_ws, size_t ws_size,
                              hipStream_t stream) {
  const float* x    = (const float*)d_in[0];
  const int*   ei   = (const int*)  d_in[1];   // [2, E] int32; row 0 = src
  const float* attr = (const float*)d_in[2];
  const float* Wp   = (const float*)d_in[3];
  const float* bp   = (const float*)d_in[4];
  const float* Wm1  = (const float*)d_in[5];
  const float* bm1  = (const float*)d_in[6];
  const float* Wm2  = (const float*)d_in[7];
  const float* bm2  = (const float*)d_in[8];
  const float* Wu1  = (const float*)d_in[9];
  const float* bu1  = (const float*)d_in[10];
  const float* Wu2  = (const float*)d_in[11];
  const float* bu2  = (const float*)d_in[12];
  float* h = (float*)d_out;   // h state lives directly in d_out

  const size_t plane = (size_t)NN * HID * sizeof(bf16_t);   // 2 MB each
  const bool sent = ws_size >= 2 * plane;
  bf16_t* h2hi = (bf16_t*)d_ws;
  bf16_t* h2lo = (bf16_t*)((char*)d_ws + plane);
  int* flags   = (int*)d_ws;
  const int fs = sent ? 0 : ((ws_size >= (size_t)NN * 64 + 64) ? 16 : 1);

  k_h0<<<NN / 8, 128, 0, stream>>>(x, Wp, bp, h, h2hi, h2lo, flags, fs,
                                   sent ? 1 : 0);
  if (sent)
    k_dag<true><<<NBLK, 256, 0, stream>>>(ei, attr, Wm1, bm1, Wm2, bm2,
                                          Wu1, bu1, Wu2, bu2, h, h2hi, h2lo,
                                          flags, fs);
  else
    k_dag<false><<<NBLK, 256, 0, stream>>>(ei, attr, Wm1, bm1, Wm2, bm2,
                                           Wu1, bu1, Wu2, bu2, h, h2hi, h2lo,
                                           flags, fs);
}